// Round 4
// baseline (487.370 us; speedup 1.0000x reference)
//
#include <hip/hip_runtime.h>
#include <hip/hip_bf16.h>
#include <stdint.h>

#define N_NODES 20000
#define E_EDGES 320000
#define IN_F    128
#define HIDF    256
#define R_REL   4
#define NRKEYS  (N_NODES*R_REL)   // 80000
#define SCAN_BLOCKS 80            // 80*1024 = 81920 >= NRKEYS

typedef __attribute__((ext_vector_type(8))) short  short8;
typedef __attribute__((ext_vector_type(4))) float  floatx4;

__device__ __forceinline__ float bf2f(__hip_bfloat16 v){ return __bfloat162float(v); }
__device__ __forceinline__ __hip_bfloat16 f2bf(float v){ return __float2bfloat16(v); }
__device__ __forceinline__ float bfbits2f(unsigned short u){ return __uint_as_float(((unsigned)u)<<16); }
__device__ __forceinline__ unsigned short f2bfbits(float v){
    __hip_bfloat16 h = __float2bfloat16(v);
    return *(unsigned short*)&h;
}
__device__ __forceinline__ unsigned pack_bf2(float a, float b){
    return (unsigned)f2bfbits(a) | ((unsigned)f2bfbits(b) << 16);
}

// async global->LDS, 16B per lane. LDS dest is WAVE-UNIFORM base (+lane*16 by HW);
// global src is per-lane (pre-swizzled to implement the LDS XOR layout).
__device__ __forceinline__ void gload_lds16(const void* g, void* l)
{
    __builtin_amdgcn_global_load_lds((const __attribute__((address_space(1))) void*)g,
                                     (__attribute__((address_space(3))) void*)l, 16, 0, 0);
}

template<int N>
__device__ __forceinline__ void wait_vm()
{
    if constexpr (N == 0)      asm volatile("s_waitcnt vmcnt(0)" ::: "memory");
    else if constexpr (N == 3) asm volatile("s_waitcnt vmcnt(3)" ::: "memory");
    else if constexpr (N == 4) asm volatile("s_waitcnt vmcnt(4)" ::: "memory");
    else                       asm volatile("s_waitcnt vmcnt(0)" ::: "memory");
}

// bijective XCD-chunked swizzle (m204 formula): blocks remapped so each XCD owns a
// contiguous j-range; decomposing j with y FASTEST puts all column-tiles of the
// same A-panel on the SAME XCD back-to-back -> A-panel read from HBM once, then
// L2-hits instead of L3/HBM for the other y's. (Verified r2: FETCH 63.6->17.3 MB.)
__device__ __forceinline__ int2 xcd_swizzle()
{
    int gx = gridDim.x, gy = gridDim.y;
    int nwg = gx * gy;
    int lin = blockIdx.x + gx * blockIdx.y;
    int q = nwg >> 3, r = nwg & 7;
    int k = lin & 7, i = lin >> 3;
    int j = (k < r ? k*(q+1) : r*(q+1) + (k-r)*q) + i;
    return make_int2(j / gy, j % gy);   // (x tile, y tile), y fastest
}

// ---------------- CSR build ----------------
__global__ void count_kernel(const int* __restrict__ ei, const int* __restrict__ et,
                             int* __restrict__ cnt)
{
    int e = blockIdx.x*256 + threadIdx.x;
    if (e >= E_EDGES) return;
    int dst = ei[E_EDGES + e];
    atomicAdd(&cnt[dst*R_REL + et[e]], 1);
}

// 3-phase parallel exclusive scan over cnt[NRKEYS] -> row_ptr, cursor
__global__ __launch_bounds__(1024) void scan_reduce_kernel(const int* __restrict__ cnt,
                                                           int* __restrict__ blocksum)
{
    int ix = blockIdx.x*1024 + threadIdx.x;
    int v = (ix < NRKEYS) ? cnt[ix] : 0;
    #pragma unroll
    for (int o=32;o>0;o>>=1) v += __shfl_xor(v, o, 64);
    __shared__ int wsum[16];
    int wave = threadIdx.x >> 6, lane = threadIdx.x & 63;
    if (lane == 0) wsum[wave] = v;
    __syncthreads();
    if (threadIdx.x == 0) {
        int s = 0;
        #pragma unroll
        for (int w=0;w<16;w++) s += wsum[w];
        blocksum[blockIdx.x] = s;
    }
}

__global__ __launch_bounds__(128) void scan_sums_kernel(const int* __restrict__ blocksum,
                                                        int* __restrict__ blockoff)
{
    __shared__ int s[128];
    int t = threadIdx.x;
    int v = (t < SCAN_BLOCKS) ? blocksum[t] : 0;
    s[t] = v; __syncthreads();
    for (int off=1; off<128; off<<=1) {
        int u = (t>=off) ? s[t-off] : 0;
        __syncthreads();
        s[t] += u;
        __syncthreads();
    }
    if (t < SCAN_BLOCKS) blockoff[t] = s[t] - v;   // exclusive
}

__global__ __launch_bounds__(1024) void scan_apply_kernel(const int* __restrict__ cnt,
                                                          const int* __restrict__ blockoff,
                                                          int* __restrict__ row_ptr,
                                                          int* __restrict__ cursor)
{
    __shared__ int s[1024];
    int t = threadIdx.x;
    int ix = blockIdx.x*1024 + t;
    int v = (ix < NRKEYS) ? cnt[ix] : 0;
    s[t] = v; __syncthreads();
    for (int off=1; off<1024; off<<=1) {
        int u = (t>=off) ? s[t-off] : 0;
        __syncthreads();
        s[t] += u;
        __syncthreads();
    }
    if (ix < NRKEYS) {
        int excl = blockoff[blockIdx.x] + s[t] - v;
        row_ptr[ix] = excl;
        cursor[ix]  = excl;
        if (ix == NRKEYS-1) row_ptr[NRKEYS] = excl + v;
    }
}

__global__ void fill_kernel(const int* __restrict__ ei, const int* __restrict__ et,
                            int* __restrict__ cursor, int* __restrict__ csr_src)
{
    int e = blockIdx.x*256 + threadIdx.x;
    if (e >= E_EDGES) return;
    int src = ei[e];
    int dst = ei[E_EDGES + e];
    int key = dst*R_REL + et[e];
    int pos = atomicAdd(&cursor[key], 1);
    csr_src[pos] = src;
}

// ---------------- weight prep: fp32 sources -> bf16 B^T = [Nout][K] ----------------
__global__ void make_b1t(const float* __restrict__ root1,
                         const float* __restrict__ W1,
                         __hip_bfloat16* __restrict__ B1t)
{
    int idx = blockIdx.x*256 + threadIdx.x;         // n*640 + k
    if (idx >= 256*640) return;
    int n = idx / 640, k = idx % 640;
    float v;
    if (k < 128) v = root1[k*256 + n];
    else         v = W1[(k-128)*256 + n];           // W1 contiguous [R*128][256]
    B1t[idx] = f2bf(v);
}

__global__ void make_b2t(const float* __restrict__ root2,
                         const float* __restrict__ W2,
                         __hip_bfloat16* __restrict__ B2t)
{
    int idx = blockIdx.x*256 + threadIdx.x;         // n*1280 + k
    if (idx >= 256*1280) return;
    int n = idx / 1280, k = idx % 1280;
    float v;
    if (k < 256) v = root2[k*256 + n];
    else         v = W2[(k-256)*256 + n];           // W2 contiguous [R*256][256]
    B2t[idx] = f2bf(v);
}

__global__ void make_b3t(const float* __restrict__ Wq, const float* __restrict__ Wk,
                         const float* __restrict__ Wv, const float* __restrict__ Wsk,
                         const float* __restrict__ bq, const float* __restrict__ bk,
                         const float* __restrict__ bv, const float* __restrict__ bsk,
                         __hip_bfloat16* __restrict__ B3t, float* __restrict__ bias3)
{
    int idx = blockIdx.x*256 + threadIdx.x;         // n*256 + k, n<1024
    if (idx >= 1024*256) return;
    int n = idx / 256, k = idx % 256;
    int g = n >> 8, nn = n & 255;
    const float* W = (g==0)?Wq:(g==1)?Wk:(g==2)?Wv:Wsk;
    B3t[idx] = f2bf(W[k*256 + nn]);
    if (k == 0) {
        const float* B = (g==0)?bq:(g==1)?bk:(g==2)?bv:bsk;
        bias3[n] = B[nn];
    }
}

// generic fp32 -> bf16 elementwise convert (layout-preserving)
__global__ void cvt_f32_bf16(const float* __restrict__ in, __hip_bfloat16* __restrict__ out, int n)
{
    int i = blockIdx.x*256 + threadIdx.x;
    if (i < n) out[i] = f2bf(in[i]);
}

// ---------------- RGCN aggregation: one WAVE per (node,rel) key, unroll-4 ILP ----------------
// agg1: x fp32 [N,128]; lane covers dims 2*lane..2*lane+1 (float2, 8 B)
__global__ __launch_bounds__(256) void agg1_kernel(const float* __restrict__ x,
                                                   const int* __restrict__ row_ptr,
                                                   const int* __restrict__ csr_src,
                                                   __hip_bfloat16* __restrict__ A1)
{
    int b = blockIdx.x*4 + (threadIdx.x >> 6);   // key = i*4 + r
    int lane = threadIdx.x & 63;
    int i = b >> 2, r = b & 3;
    int e0 = row_ptr[b], e1 = row_ptr[b+1];
    float sx0=0.f,sy0=0.f, sx1=0.f,sy1=0.f, sx2=0.f,sy2=0.f, sx3=0.f,sy3=0.f;
    int e = e0;
    for (; e+4 <= e1; e += 4) {
        int i0=csr_src[e], i1=csr_src[e+1], i2=csr_src[e+2], i3=csr_src[e+3];
        float2 v0 = *(const float2*)(x + (size_t)i0*IN_F + lane*2);
        float2 v1 = *(const float2*)(x + (size_t)i1*IN_F + lane*2);
        float2 v2 = *(const float2*)(x + (size_t)i2*IN_F + lane*2);
        float2 v3 = *(const float2*)(x + (size_t)i3*IN_F + lane*2);
        sx0+=v0.x; sy0+=v0.y; sx1+=v1.x; sy1+=v1.y;
        sx2+=v2.x; sy2+=v2.y; sx3+=v3.x; sy3+=v3.y;
    }
    for (; e < e1; e++) {
        int i0 = csr_src[e];
        float2 v = *(const float2*)(x + (size_t)i0*IN_F + lane*2);
        sx0+=v.x; sy0+=v.y;
    }
    float sx = (sx0+sx1)+(sx2+sx3);
    float sy = (sy0+sy1)+(sy2+sy3);
    float inv = (e1>e0) ? 1.f/(float)(e1-e0) : 0.f;
    *(unsigned*)(A1 + (size_t)i*640 + 128 + r*128 + lane*2) = pack_bf2(sx*inv, sy*inv);
    if (r == 0) {
        float2 v = *(const float2*)(x + (size_t)i*IN_F + lane*2);
        *(unsigned*)(A1 + (size_t)i*640 + lane*2) = pack_bf2(v.x, v.y);
    }
}

// agg2: h1 bf16 in A2 cols 0..255 (ld 1280); lane covers dims 4*lane..4*lane+3 (ushort4, 8 B)
__global__ __launch_bounds__(256) void agg2_kernel(const int* __restrict__ row_ptr,
                                                   const int* __restrict__ csr_src,
                                                   __hip_bfloat16* __restrict__ A2)
{
    int b = blockIdx.x*4 + (threadIdx.x >> 6);
    int lane = threadIdx.x & 63;
    int i = b >> 2, r = b & 3;
    int e0 = row_ptr[b], e1 = row_ptr[b+1];
    float a0=0.f,a1=0.f,a2=0.f,a3=0.f;
    float b0=0.f,b1=0.f,b2=0.f,b3=0.f;
    float c0=0.f,c1=0.f,c2=0.f,c3=0.f;
    float d0=0.f,d1=0.f,d2=0.f,d3=0.f;
    int e = e0;
    for (; e+4 <= e1; e += 4) {
        int i0=csr_src[e], i1=csr_src[e+1], i2=csr_src[e+2], i3=csr_src[e+3];
        ushort4 u0 = *(const ushort4*)(A2 + (size_t)i0*1280 + lane*4);
        ushort4 u1 = *(const ushort4*)(A2 + (size_t)i1*1280 + lane*4);
        ushort4 u2 = *(const ushort4*)(A2 + (size_t)i2*1280 + lane*4);
        ushort4 u3 = *(const ushort4*)(A2 + (size_t)i3*1280 + lane*4);
        a0+=bfbits2f(u0.x); a1+=bfbits2f(u0.y); a2+=bfbits2f(u0.z); a3+=bfbits2f(u0.w);
        b0+=bfbits2f(u1.x); b1+=bfbits2f(u1.y); b2+=bfbits2f(u1.z); b3+=bfbits2f(u1.w);
        c0+=bfbits2f(u2.x); c1+=bfbits2f(u2.y); c2+=bfbits2f(u2.z); c3+=bfbits2f(u2.w);
        d0+=bfbits2f(u3.x); d1+=bfbits2f(u3.y); d2+=bfbits2f(u3.z); d3+=bfbits2f(u3.w);
    }
    for (; e < e1; e++) {
        int i0 = csr_src[e];
        ushort4 u = *(const ushort4*)(A2 + (size_t)i0*1280 + lane*4);
        a0+=bfbits2f(u.x); a1+=bfbits2f(u.y); a2+=bfbits2f(u.z); a3+=bfbits2f(u.w);
    }
    float s0=(a0+b0)+(c0+d0), s1=(a1+b1)+(c1+d1), s2=(a2+b2)+(c2+d2), s3=(a3+b3)+(c3+d3);
    float inv = (e1>e0) ? 1.f/(float)(e1-e0) : 0.f;
    uint2 w;
    w.x = pack_bf2(s0*inv, s1*inv);
    w.y = pack_bf2(s2*inv, s3*inv);
    *(uint2*)(A2 + (size_t)i*1280 + 256 + r*256 + lane*4) = w;
}

// ---------------- LDS-pipelined GEMM (long-K: gemm1 K=640, gemm2 K=1280) ----------------
// r2 config (best measured): triple-buffered global_load_lds, 2 batches in flight,
// counted vmcnt(L). Chunk-XOR LDS swizzle via pre-swizzled global source
// (SQ_LDS_BANK_CONFLICT = 0, verified r1). XCD swizzle (FETCH compulsory, r2).
template<int MI>
__device__ __forceinline__ void gemm_bt_body(const __hip_bfloat16* __restrict__ A, int lda,
                                             const __hip_bfloat16* __restrict__ Bt,
                                             const float* __restrict__ bias,
                                             __hip_bfloat16* __restrict__ C, int ldc,
                                             int M, int K, int relu,
                                             int tile_m, int tile_n,
                                             __hip_bfloat16* lds_a, __hip_bfloat16* lds_b)
{
    constexpr int A_ELEMS = MI*1024;   // elems per A tile buffer ((MI*32) rows x 32)
    constexpr int B_ELEMS = 4096;      // 128 rows x 32
    constexpr int L = MI/2 + 2;        // gload_lds instrs per wave per batch
    const int tid  = threadIdx.x;
    const int wave = tid >> 6;
    const int lane = tid & 63;
    const int wm = wave >> 1, wn = wave & 1;     // 2x2 wave grid
    const int fm = lane & 15;
    const int q  = lane >> 4;
    const int sw = (q ^ ((fm >> 1) & 3)) * 8;    // swizzled 16B chunk (elem offset)

    floatx4 acc[MI][4];
    #pragma unroll
    for (int i=0;i<MI;i++)
        #pragma unroll
        for (int j=0;j<4;j++) acc[i][j] = (floatx4){0.f,0.f,0.f,0.f};

    // staging descriptors: thread covers row seg*16 + lane/4, phys slot lane&3.
    // inverse-swizzle the global chunk so linear LDS write == swizzled layout.
    const int srow   = lane >> 2;                // 0..15
    const int schunk = lane & 3;
    size_t a_goff[MI/2];
    #pragma unroll
    for (int s = 0; s < MI/2; ++s) {
        int r = (s*4 + wave)*16 + srow;
        int c = schunk ^ ((r >> 1) & 3);
        a_goff[s] = (size_t)min(tile_m + r, M-1)*lda + c*8;
    }
    size_t b_goff[2];
    #pragma unroll
    for (int s = 0; s < 2; ++s) {
        int r = (s*4 + wave)*16 + srow;
        int c = schunk ^ ((r >> 1) & 3);
        b_goff[s] = (size_t)(tile_n + r)*K + c*8;
    }

    const int nt = K >> 5;

    auto issue = [&](int t, int bufi) {
        const int kn = t << 5;
        #pragma unroll
        for (int s = 0; s < MI/2; ++s)
            gload_lds16(A + a_goff[s] + kn, lds_a + bufi*A_ELEMS + (s*4 + wave)*512);
        #pragma unroll
        for (int s = 0; s < 2; ++s)
            gload_lds16(Bt + b_goff[s] + kn, lds_b + bufi*B_ELEMS + (s*4 + wave)*512);
    };

    // prologue: batches 0 and 1 in flight; only batch 0 must land before step 0
    issue(0, 0);
    if (nt > 1) { issue(1, 1); wait_vm<L>(); }
    else        { wait_vm<0>(); }
    __builtin_amdgcn_s_barrier();

    int cur = 0, nx2 = 2;
    for (int t = 0; t < nt; ++t) {
        if (t + 2 < nt) issue(t + 2, nx2);       // keep 2 batches in flight

        const __hip_bfloat16* la = lds_a + cur*A_ELEMS;
        const __hip_bfloat16* lb = lds_b + cur*B_ELEMS;
        short8 afr[MI], bfr[4];
        #pragma unroll
        for (int i=0;i<MI;i++)
            afr[i] = *(const short8*)(la + (wm*(MI*16) + i*16 + fm)*32 + sw);
        #pragma unroll
        for (int j=0;j<4;j++)
            bfr[j] = *(const short8*)(lb + (wn*64 + j*16 + fm)*32 + sw);

        __builtin_amdgcn_s_setprio(1);
        #pragma unroll
        for (int i=0;i<MI;i++)
            #pragma unroll
            for (int j=0;j<4;j++)
                acc[i][j] = __builtin_amdgcn_mfma_f32_16x16x32_bf16(afr[i], bfr[j], acc[i][j], 0,0,0);
        __builtin_amdgcn_s_setprio(0);

        if (t + 1 < nt) {
            if (t + 2 < nt) wait_vm<L>();        // batch t+1 landed; t+2 stays in flight
            else            wait_vm<0>();        // tail: drain
            __builtin_amdgcn_s_barrier();
            cur = (cur == 2) ? 0 : cur + 1;
            nx2 = (nx2 == 2) ? 0 : nx2 + 1;
        }
    }

    const int crow_base = tile_m + wm*(MI*16);
    const int ccol_base = tile_n + wn*64;
    #pragma unroll
    for (int i=0;i<MI;i++) {
        #pragma unroll
        for (int j=0;j<4;j++) {
            int c  = ccol_base + j*16 + fm;
            float bb = bias[c];
            #pragma unroll
            for (int rg=0; rg<4; rg++) {
                int r = crow_base + i*16 + q*4 + rg;
                if (r < M) {
                    float v = acc[i][j][rg] + bb;
                    if (relu) v = fmaxf(v, 0.f);
                    C[(size_t)r*ldc + c] = f2bf(v);
                }
            }
        }
    }
}

template<int MI>
__global__ __launch_bounds__(256) void gemm_bt_t(const __hip_bfloat16* __restrict__ A, int lda,
                                                 const __hip_bfloat16* __restrict__ Bt,
                                                 const float* __restrict__ bias,
                                                 __hip_bfloat16* __restrict__ C, int ldc,
                                                 int M, int K, int relu)
{
    __shared__ __align__(16) __hip_bfloat16 lds_a[3*MI*1024];
    __shared__ __align__(16) __hip_bfloat16 lds_b[3*4096];
    int2 xy = xcd_swizzle();
    gemm_bt_body<MI>(A, lda, Bt, bias, C, ldc, M, K, relu,
                     xy.x*(MI*32), xy.y*128, lds_a, lds_b);
}

// ---------------- wave-independent register GEMM (K=256: gemm3, GRU dual) ----------------
// r3 lesson: barrier-lockstep + LDS depth trades TLP for ILP at a net loss. Here
// K=256 and both operands are L2-resident (XCD swizzle, FETCH compulsory since r2),
// so each wave computes an independent 64x64 tile with NO LDS and NO barriers:
// fragments load straight from global (same geometry as the old ds_read_b128),
// fully-unrolled 8-step K-loop (64 loads + 128 MFMA straight-line), compiler
// schedules counted vmcnt freely. Latency hiding = many independent waves/CU.
// All K-offsets fold into 13-bit load immediates off 8 lane-base pointers.
__device__ __forceinline__ void gemm_wave_body(const __hip_bfloat16* __restrict__ A,
                                               const __hip_bfloat16* __restrict__ Bt,
                                               const float* __restrict__ bias,
                                               __hip_bfloat16* __restrict__ C, int ldc,
                                               int M, int tile_m, int tile_n)
{
    const int lane = threadIdx.x & 63;
    const int fm = lane & 15;
    const int q  = lane >> 4;

    floatx4 acc[4][4];
    #pragma unroll
    for (int i=0;i<4;i++)
        #pragma unroll
        for (int j=0;j<4;j++) acc[i][j] = (floatx4){0.f,0.f,0.f,0.f};

    const __hip_bfloat16* ap[4];
    const __hip_bfloat16* bp[4];
    #pragma unroll
    for (int i=0;i<4;i++)
        ap[i] = A + (size_t)min(tile_m + i*16 + fm, M-1)*256 + q*8;
    #pragma unroll
    for (int j=0;j<4;j++)
        bp[j] = Bt + (size_t)(tile_n + j*16 + fm)*256 + q*8;

    #pragma unroll
    for (int t = 0; t < 8; ++t) {
        short8 av[4], bv[4];
        #pragma unroll
        for (int i=0;i<4;i++) av[i] = *(const short8*)(ap[i] + t*32);
        #pragma unroll
        for (int j=0;j<4;j++) bv[j] = *(const short8*)(bp[j] + t*32);
        #pragma unroll
        for (int i=0;i<4;i++)
            #pragma unroll
            for (int j=0;j<4;j++)
                acc[i][j] = __builtin_amdgcn_mfma_f32_16x16x32_bf16(av[i], bv[j], acc[i][j], 0,0,0);
    }

    #pragma unroll
    for (int i=0;i<4;i++) {
        #pragma unroll
        for (int j=0;j<4;j++) {
            int c  = tile_n + j*16 + fm;
            float bb = bias[c];
            #pragma unroll
            for (int rg=0; rg<4; rg++) {
                int r = tile_m + i*16 + q*4 + rg;
                if (r < M) C[(size_t)r*ldc + c] = f2bf(acc[i][j][rg] + bb);
            }
        }
    }
}

// gemm3: qkvs = h2 * B3t^T + bias3.  grid (313, 4); wave w covers cols y*256+w*64.
__global__ __launch_bounds__(256) void gemm_wave_single(const __hip_bfloat16* __restrict__ A,
                                                        const __hip_bfloat16* __restrict__ Bt,
                                                        const float* __restrict__ bias,
                                                        __hip_bfloat16* __restrict__ C, int ldc)
{
    int2 xy = xcd_swizzle();
    int wave = threadIdx.x >> 6;
    gemm_wave_body(A, Bt, bias, C, ldc, N_NODES, xy.x*64, xy.y*256 + wave*64);
}

// GRU gates: two independent GEMMs (M=N, K=256, Nout=768) in one dispatch.
// grid (313, 6): y in [0,3) -> problem 0, [3,6) -> problem 1; y-fastest XCD
// swizzle keeps both problems' A panels for the same rows on one XCD.
__global__ __launch_bounds__(256) void gemm_wave_dual(const __hip_bfloat16* __restrict__ A0,
                                                      const __hip_bfloat16* __restrict__ A1,
                                                      const __hip_bfloat16* __restrict__ Bt0,
                                                      const __hip_bfloat16* __restrict__ Bt1,
                                                      const float* __restrict__ bias0,
                                                      const float* __restrict__ bias1,
                                                      __hip_bfloat16* __restrict__ C0,
                                                      __hip_bfloat16* __restrict__ C1)
{
    int2 xy = xcd_swizzle();
    int wave = threadIdx.x >> 6;
    int which = xy.y >= 3;
    int ny    = which ? (xy.y - 3) : xy.y;
    gemm_wave_body(which ? A1 : A0,
                   which ? Bt1 : Bt0,
                   which ? bias1 : bias0,
                   which ? C1 : C0, 768,
                   N_NODES, xy.x*64, ny*256 + wave*64);
}

// ---------------- attention scores: ONE WAVE PER NODE ----------------
__global__ __launch_bounds__(256) void score_kernel(const __hip_bfloat16* __restrict__ qkvs,
                                                    const int* __restrict__ row_ptr,
                                                    const int* __restrict__ csr_src,
                                                    float* __restrict__ score)
{
    int i = blockIdx.x*4 + (threadIdx.x >> 6);
    int lane = threadIdx.x & 63;
    int h = lane >> 4, d4 = lane & 15;
    int e0 = row_ptr[i*R_REL], e1 = row_ptr[i*R_REL + R_REL];
    ushort4 qv = *(const ushort4*)(qkvs + (size_t)i*1024 + lane*4);
    float qx=bfbits2f(qv.x), qy=bfbits2f(qv.y), qz=bfbits2f(qv.z), qw=bfbits2f(qv.w);
    float* sp = score + (size_t)h*E_EDGES;
    int j = e0;
    for (; j+2 <= e1; j += 2) {
        int s0 = csr_src[j], s1 = csr_src[j+1];
        ushort4 k0 = *(const ushort4*)(qkvs + (size_t)s0*1024 + 256 + lane*4);
        ushort4 k1 = *(const ushort4*)(qkvs + (size_t)s1*1024 + 256 + lane*4);
        float d0 = qx*bfbits2f(k0.x)+qy*bfbits2f(k0.y)+qz*bfbits2f(k0.z)+qw*bfbits2f(k0.w);
        float d1 = qx*bfbits2f(k1.x)+qy*bfbits2f(k1.y)+qz*bfbits2f(k1.z)+qw*bfbits2f(k1.w);
        #pragma unroll
        for (int o=1;o<16;o<<=1){ d0 += __shfl_xor(d0,o,64); d1 += __shfl_xor(d1,o,64); }
        if (d4 == 0) { sp[j] = d0*0.125f; sp[j+1] = d1*0.125f; }
    }
    for (; j < e1; j++) {
        int s0 = csr_src[j];
        ushort4 k0 = *(const ushort4*)(qkvs + (size_t)s0*1024 + 256 + lane*4);
        float d0 = qx*bfbits2f(k0.x)+qy*bfbits2f(k0.y)+qz*bfbits2f(k0.z)+qw*bfbits2f(k0.w);
        #pragma unroll
        for (int o=1;o<16;o<<=1) d0 += __shfl_xor(d0,o,64);
        if (d4 == 0) sp[j] = d0*0.125f;
    }
}

// ---------------- attention aggregate: ONE WAVE PER NODE, all 4 heads ----------------
__global__ __launch_bounds__(256) void attn_agg_kernel(const __hip_bfloat16* __restrict__ qkvs,
                                                       const float* __restrict__ score,
                                                       const int* __restrict__ row_ptr,
                                                       const int* __restrict__ csr_src,
                                                       __hip_bfloat16* __restrict__ hatt)
{
    int i = blockIdx.x*4 + (threadIdx.x >> 6);   // node (4 nodes per block)
    int lane = threadIdx.x & 63;
    int h  = lane >> 4;
    int d4 = lane & 15;
    int e0 = row_ptr[i*R_REL], e1 = row_ptr[i*R_REL + R_REL];
    int deg = e1 - e0;
    const float* sp = score + (size_t)h*E_EDGES + e0;

    // pass 1: per-head max
    float m = -1e30f;
    for (int j = d4; j < deg; j += 16) m = fmaxf(m, sp[j]);
    #pragma unroll
    for (int o=1;o<16;o<<=1) m = fmaxf(m, __shfl_xor(m, o, 64));

    // pass 2: per-head denom
    float ssum = 0.f;
    for (int j = d4; j < deg; j += 16) ssum += __expf(sp[j] - m);
    #pragma unroll
    for (int o=1;o<16;o<<=1) ssum += __shfl_xor(ssum, o, 64);
    float inv = 1.f / fmaxf(ssum, 1e-16f);

    // pass 3: all lanes walk all edges (unroll 4), no cross-lane reduction
    float ax=0.f, ay=0.f, az=0.f, aw=0.f;
    int j = 0;
    for (; j+4 <= deg; j += 4) {
        int s0=csr_src[e0+j], s1=csr_src[e0+j+1], s2=csr_src[e0+j+2], s3=csr_src[e0+j+3];
        float w0 = __expf(sp[j]   - m) * inv;
        float w1 = __expf(sp[j+1] - m) * inv;
        float w2 = __expf(sp[j+2] - m) * inv;
        float w3 = __expf(sp[j+3] - m) * inv;
        ushort4 u0 = *(const ushort4*)(qkvs + (size_t)s0*1024 + 512 + lane*4);
        ushort4 u1 = *(const ushort4*)(qkvs + (size_t)s1*1024 + 512 + lane*4);
        ushort4 u2 = *(const ushort4*)(qkvs + (size_t)s2*1024 + 512 + lane*4);
        ushort4 u3 = *(const ushort4*)(qkvs + (size_t)s3*1024 + 512 + lane*4);
        ax += w0*bfbits2f(u0.x) + w1*bfbits2f(u1.x) + w2*bfbits2f(u2.x) + w3*bfbits2f(u3.x);
        ay += w0*bfbits2f(u0.y) + w1*bfbits2f(u1.y) + w2*bfbits2f(u2.y) + w3*bfbits2f(u3.y);
        az += w0*bfbits2f(u0.z) + w1*bfbits2f(u1.z) + w2*bfbits2f(u2.z) + w3*bfbits2f(u3.z);
        aw += w0*bfbits2f(u0.w) + w1*bfbits2f(u1.w) + w2*bfbits2f(u2.w) + w3*bfbits2f(u3.w);
    }
    for (; j < deg; j++) {
        int s = csr_src[e0+j];
        float w = __expf(sp[j] - m) * inv;
        ushort4 u = *(const ushort4*)(qkvs + (size_t)s*1024 + 512 + lane*4);
        ax += w*bfbits2f(u.x); ay += w*bfbits2f(u.y);
        az += w*bfbits2f(u.z); aw += w*bfbits2f(u.w);
    }
    ushort4 sk = *(const ushort4*)(qkvs + (size_t)i*1024 + 768 + lane*4);
    uint2 w;
    w.x = pack_bf2(ax + bfbits2f(sk.x), ay + bfbits2f(sk.y));
    w.y = pack_bf2(az + bfbits2f(sk.z), aw + bfbits2f(sk.w));
    *(uint2*)(hatt + (size_t)i*256 + lane*4) = w;
}

// ---------------- GRU elementwise (bf16 gates, fp32 math, fp32 out) ----------------
__global__ void gru_kernel(const __hip_bfloat16* __restrict__ gi,
                           const __hip_bfloat16* __restrict__ gh,
                           const float* __restrict__ hprev,
                           float* __restrict__ out)
{
    int idx = blockIdx.x*256 + threadIdx.x;
    if (idx >= N_NODES*HIDF) return;
    int i = idx / HIDF, c = idx % HIDF;
    size_t gb = (size_t)i*768;
    float ir = bf2f(gi[gb + c]), iz = bf2f(gi[gb + 256 + c]), in = bf2f(gi[gb + 512 + c]);
    float hr = bf2f(gh[gb + c]), hz = bf2f(gh[gb + 256 + c]), hn = bf2f(gh[gb + 512 + c]);
    float r = 1.f/(1.f + __expf(-(ir+hr)));
    float z = 1.f/(1.f + __expf(-(iz+hz)));
    float n = tanhf(in + r*hn);
    float h = hprev[idx];
    out[idx] = (1.f - z)*n + z*h;
}

// ---------------- launch ----------------
// Inputs fp32 (verified round 3); bf16 internally for MFMA. Workspace ~107 MB:
//   P1 (25.6 MB):  A1 -> h2 -> hatt
//   P2 (61.4 MB):  A2 -> qkvs -> (gi | gh)   (gi at 0, gh at +N*768 elements)
extern "C" void kernel_launch(void* const* d_in, const int* in_sizes, int n_in,
                              void* d_out, int out_size, void* d_ws, size_t ws_size,
                              hipStream_t stream)
{
    const float* x       = (const float*)d_in[0];
    const int* edge_index= (const int*)d_in[1];
    const int* edge_type = (const int*)d_in[2];
    const float* hprev   = (const float*)d_in[3];
    const float* W1      = (const float*)d_in[4];
    const float* root1   = (const float*)d_in[5];
    const float* b1      = (const float*)d_in[6];
    const float* W2      = (const float*)d_in[7];
    const float* root2   = (const float*)d_in[8];
    const float* b2      = (const float*)d_in[9];
    const float* Wq      = (const float*)d_in[10];
    const float* bq      = (const float*)d_in[11];
    const float* Wk      = (const float*)d_in[12];
    const float* bk      = (const float*)d_in[13];
    const float* Wv      = (const float*)d_in[14];
    const float* bv      = (const float*)d_in[15];
    const float* Wskip   = (const float*)d_in[16];
    const float* bskip   = (const float*)d_in[17];
    const float* W_ih    = (const float*)d_in[18];
    const float* b_ih    = (const float*)d_in[19];
    const float* W_hh    = (const float*)d_in[20];
    const float* b_hh    = (const float*)d_in[21];

    char* ws = (char*)d_ws;
    size_t off = 0;
    auto take = [&](size_t bytes)->char* {
        char* p = ws + off;
        off = (off + bytes + 255) & ~(size_t)255;
        return p;
    };
    int* cnt        = (int*)take((size_t)NRKEYS*4);
    int* row_ptr    = (int*)take((size_t)(NRKEYS+1)*4);
    int* cursor     = (int*)take((size_t)NRKEYS*4);
    int* csr_src    = (int*)take((size_t)E_EDGES*4);
    int* blocksum   = (int*)take((size_t)SCAN_BLOCKS*4);
    int* blockoff   = (int*)take((size_t)(SCAN_BLOCKS+1)*4);
    float* score    = (float*)take((size_t)R_REL*E_EDGES*4);   // [HEADS][E], CSR-position-indexed
    __hip_bfloat16* B1t   = (__hip_bfloat16*)take((size_t)256*640*2);
    __hip_bfloat16* B2t   = (__hip_bfloat16*)take((size_t)256*1280*2);
    __hip_bfloat16* B3t   = (__hip_bfloat16*)take((size_t)1024*256*2);
    __hip_bfloat16* Biht  = (__hip_bfloat16*)take((size_t)768*256*2);
    __hip_bfloat16* Bhht  = (__hip_bfloat16*)take((size_t)768*256*2);
    float*          bias3 = (float*)take((size_t)1024*4);
    __hip_bfloat16* hprev_bf = (__hip_bfloat16*)take((size_t)N_NODES*256*2);
    // P1: max(A1 N*640, h2 N*256, hatt N*256) bf16
    char* P1 = take((size_t)N_NODES*640*2);
    // P2: max(A2 N*1280, qkvs N*1024, gi+gh N*1536) bf16
    char* P2 = take((size_t)N_NODES*1536*2);

    __hip_bfloat16* A1   = (__hip_bfloat16*)P1;   // [N,640]  dead after gemm1
    __hip_bfloat16* h2   = (__hip_bfloat16*)P1;   // [N,256]  dead after gemm3
    __hip_bfloat16* hatt = (__hip_bfloat16*)P1;   // [N,256]  read by gemm45
    __hip_bfloat16* A2   = (__hip_bfloat16*)P2;   // [N,1280] dead after gemm2
    __hip_bfloat16* qkvs = (__hip_bfloat16*)P2;   // [N,1024] dead after attn_agg
    __hip_bfloat16* gi   = (__hip_bfloat16*)P2;                          // [N,768]
    __hip_bfloat16* gh   = (__hip_bfloat16*)(P2 + (size_t)N_NODES*768*2); // [N,768]

    hipMemsetAsync(cnt, 0, (size_t)NRKEYS*4, stream);
    count_kernel<<<(E_EDGES+255)/256, 256, 0, stream>>>(edge_index, edge_type, cnt);
    scan_reduce_kernel<<<SCAN_BLOCKS, 1024, 0, stream>>>(cnt, blocksum);
    scan_sums_kernel<<<1, 128, 0, stream>>>(blocksum, blockoff);
    scan_apply_kernel<<<SCAN_BLOCKS, 1024, 0, stream>>>(cnt, blockoff, row_ptr, cursor);
    fill_kernel<<<(E_EDGES+255)/256, 256, 0, stream>>>(edge_index, edge_type, cursor, csr_src);

    make_b1t<<<(256*640+255)/256, 256, 0, stream>>>(root1, W1, B1t);
    make_b2t<<<(256*1280+255)/256, 256, 0, stream>>>(root2, W2, B2t);
    make_b3t<<<(1024*256+255)/256, 256, 0, stream>>>(Wq, Wk, Wv, Wskip, bq, bk, bv, bskip, B3t, bias3);
    cvt_f32_bf16<<<(768*256+255)/256, 256, 0, stream>>>(W_ih, Biht, 768*256);
    cvt_f32_bf16<<<(768*256+255)/256, 256, 0, stream>>>(W_hh, Bhht, 768*256);
    cvt_f32_bf16<<<(N_NODES*256+255)/256, 256, 0, stream>>>(hprev, hprev_bf, N_NODES*256);

    // one wave per (node,rel) key; block covers node's 4 rels
    agg1_kernel<<<NRKEYS/4, 256, 0, stream>>>(x, row_ptr, csr_src, A1);

    // h1 = relu(A1 * B1) written into A2 cols 0..255 (ldc=1280)
    dim3 g12(313, 2);
    gemm_bt_t<2><<<g12, 256, 0, stream>>>(A1, 640, B1t, b1, A2, 1280, N_NODES, 640, 1);

    agg2_kernel<<<NRKEYS/4, 256, 0, stream>>>(row_ptr, csr_src, A2);

    // h2 overwrites A1 (dead) in P1
    gemm_bt_t<2><<<g12, 256, 0, stream>>>(A2, 1280, B2t, b2, h2, 256, N_NODES, 1280, 1);

    // qkvs overwrites A2 (dead) in P2 — wave-independent register GEMM
    gemm_wave_single<<<dim3(313, 4), 256, 0, stream>>>(h2, B3t, bias3, qkvs, 1024);

    // attention: one-wave-per-node scores, then one-wave-per-node aggregate
    score_kernel<<<N_NODES/4, 256, 0, stream>>>(qkvs, row_ptr, csr_src, score);
    attn_agg_kernel<<<N_NODES/4, 256, 0, stream>>>(qkvs, score, row_ptr, csr_src, hatt);

    // fused GRU gate GEMMs (wave-independent): gi = hatt*W_ih^T ; gh = hprev*W_hh^T
    gemm_wave_dual<<<dim3(313, 6), 256, 0, stream>>>(hatt, hprev_bf, Biht, Bhht, b_ih, b_hh, gi, gh);

    gru_kernel<<<(N_NODES*HIDF+255)/256, 256, 0, stream>>>(gi, gh, hprev, (float*)d_out);
}

// Round 5
// 431.154 us; speedup vs baseline: 1.1304x; 1.1304x over previous
//
#include <hip/hip_runtime.h>
#include <hip/hip_bf16.h>
#include <stdint.h>

#define N_NODES 20000
#define E_EDGES 320000
#define IN_F    128
#define HIDF    256
#define R_REL   4
#define NRKEYS  (N_NODES*R_REL)   // 80000
#define SCAN_BLOCKS 80            // 80*1024 = 81920 >= NRKEYS

typedef __attribute__((ext_vector_type(8))) short  short8;
typedef __attribute__((ext_vector_type(4))) float  floatx4;

__device__ __forceinline__ float bf2f(__hip_bfloat16 v){ return __bfloat162float(v); }
__device__ __forceinline__ __hip_bfloat16 f2bf(float v){ return __float2bfloat16(v); }
__device__ __forceinline__ float bfbits2f(unsigned short u){ return __uint_as_float(((unsigned)u)<<16); }
__device__ __forceinline__ unsigned short f2bfbits(float v){
    __hip_bfloat16 h = __float2bfloat16(v);
    return *(unsigned short*)&h;
}
__device__ __forceinline__ unsigned pack_bf2(float a, float b){
    return (unsigned)f2bfbits(a) | ((unsigned)f2bfbits(b) << 16);
}

// async global->LDS, 16B per lane. LDS dest is WAVE-UNIFORM base (+lane*16 by HW);
// global src is per-lane (pre-swizzled to implement the LDS XOR layout).
__device__ __forceinline__ void gload_lds16(const void* g, void* l)
{
    __builtin_amdgcn_global_load_lds((const __attribute__((address_space(1))) void*)g,
                                     (__attribute__((address_space(3))) void*)l, 16, 0, 0);
}

template<int N>
__device__ __forceinline__ void wait_vm()
{
    if constexpr (N == 0)      asm volatile("s_waitcnt vmcnt(0)" ::: "memory");
    else if constexpr (N == 3) asm volatile("s_waitcnt vmcnt(3)" ::: "memory");
    else if constexpr (N == 4) asm volatile("s_waitcnt vmcnt(4)" ::: "memory");
    else if constexpr (N == 5) asm volatile("s_waitcnt vmcnt(5)" ::: "memory");
    else                       asm volatile("s_waitcnt vmcnt(0)" ::: "memory");
}

// bijective XCD-chunked swizzle (m204 formula): blocks remapped so each XCD owns a
// contiguous j-range; decomposing j with y FASTEST puts all column-tiles of the
// same A-panel on the SAME XCD back-to-back -> A-panel read from HBM once, then
// L2-hits instead of L3/HBM for the other y's. (Verified r2: FETCH 63.6->17.3 MB.)
// GEMM-structure history: r3 quad-buffer depth-3 lost to occupancy (LDS 64K -> 2
// blk/CU); r4 no-LDS register GEMM lost to per-wave L2 latency (MfmaUtil 7.6%).
// The r2 triple-buffer / 2-in-flight / vmcnt(L) structure is the measured optimum.
__device__ __forceinline__ int2 xcd_swizzle()
{
    int gx = gridDim.x, gy = gridDim.y;
    int nwg = gx * gy;
    int lin = blockIdx.x + gx * blockIdx.y;
    int q = nwg >> 3, r = nwg & 7;
    int k = lin & 7, i = lin >> 3;
    int j = (k < r ? k*(q+1) : r*(q+1) + (k-r)*q) + i;
    return make_int2(j / gy, j % gy);   // (x tile, y tile), y fastest
}

// ---------------- CSR build ----------------
__global__ void count_kernel(const int* __restrict__ ei, const int* __restrict__ et,
                             int* __restrict__ cnt)
{
    int e = blockIdx.x*256 + threadIdx.x;
    if (e >= E_EDGES) return;
    int dst = ei[E_EDGES + e];
    atomicAdd(&cnt[dst*R_REL + et[e]], 1);
}

// 3-phase parallel exclusive scan over cnt[NRKEYS] -> row_ptr, cursor
__global__ __launch_bounds__(1024) void scan_reduce_kernel(const int* __restrict__ cnt,
                                                           int* __restrict__ blocksum)
{
    int ix = blockIdx.x*1024 + threadIdx.x;
    int v = (ix < NRKEYS) ? cnt[ix] : 0;
    #pragma unroll
    for (int o=32;o>0;o>>=1) v += __shfl_xor(v, o, 64);
    __shared__ int wsum[16];
    int wave = threadIdx.x >> 6, lane = threadIdx.x & 63;
    if (lane == 0) wsum[wave] = v;
    __syncthreads();
    if (threadIdx.x == 0) {
        int s = 0;
        #pragma unroll
        for (int w=0;w<16;w++) s += wsum[w];
        blocksum[blockIdx.x] = s;
    }
}

__global__ __launch_bounds__(128) void scan_sums_kernel(const int* __restrict__ blocksum,
                                                        int* __restrict__ blockoff)
{
    __shared__ int s[128];
    int t = threadIdx.x;
    int v = (t < SCAN_BLOCKS) ? blocksum[t] : 0;
    s[t] = v; __syncthreads();
    for (int off=1; off<128; off<<=1) {
        int u = (t>=off) ? s[t-off] : 0;
        __syncthreads();
        s[t] += u;
        __syncthreads();
    }
    if (t < SCAN_BLOCKS) blockoff[t] = s[t] - v;   // exclusive
}

__global__ __launch_bounds__(1024) void scan_apply_kernel(const int* __restrict__ cnt,
                                                          const int* __restrict__ blockoff,
                                                          int* __restrict__ row_ptr,
                                                          int* __restrict__ cursor)
{
    __shared__ int s[1024];
    int t = threadIdx.x;
    int ix = blockIdx.x*1024 + t;
    int v = (ix < NRKEYS) ? cnt[ix] : 0;
    s[t] = v; __syncthreads();
    for (int off=1; off<1024; off<<=1) {
        int u = (t>=off) ? s[t-off] : 0;
        __syncthreads();
        s[t] += u;
        __syncthreads();
    }
    if (ix < NRKEYS) {
        int excl = blockoff[blockIdx.x] + s[t] - v;
        row_ptr[ix] = excl;
        cursor[ix]  = excl;
        if (ix == NRKEYS-1) row_ptr[NRKEYS] = excl + v;
    }
}

__global__ void fill_kernel(const int* __restrict__ ei, const int* __restrict__ et,
                            int* __restrict__ cursor, int* __restrict__ csr_src)
{
    int e = blockIdx.x*256 + threadIdx.x;
    if (e >= E_EDGES) return;
    int src = ei[e];
    int dst = ei[E_EDGES + e];
    int key = dst*R_REL + et[e];
    int pos = atomicAdd(&cursor[key], 1);
    csr_src[pos] = src;
}

// ---------------- weight prep: fp32 sources -> bf16 B^T = [Nout][K] ----------------
__global__ void make_b1t(const float* __restrict__ root1,
                         const float* __restrict__ W1,
                         __hip_bfloat16* __restrict__ B1t)
{
    int idx = blockIdx.x*256 + threadIdx.x;         // n*640 + k
    if (idx >= 256*640) return;
    int n = idx / 640, k = idx % 640;
    float v;
    if (k < 128) v = root1[k*256 + n];
    else         v = W1[(k-128)*256 + n];           // W1 contiguous [R*128][256]
    B1t[idx] = f2bf(v);
}

__global__ void make_b2t(const float* __restrict__ root2,
                         const float* __restrict__ W2,
                         __hip_bfloat16* __restrict__ B2t)
{
    int idx = blockIdx.x*256 + threadIdx.x;         // n*1280 + k
    if (idx >= 256*1280) return;
    int n = idx / 1280, k = idx % 1280;
    float v;
    if (k < 256) v = root2[k*256 + n];
    else         v = W2[(k-256)*256 + n];           // W2 contiguous [R*256][256]
    B2t[idx] = f2bf(v);
}

__global__ void make_b3t(const float* __restrict__ Wq, const float* __restrict__ Wk,
                         const float* __restrict__ Wv, const float* __restrict__ Wsk,
                         const float* __restrict__ bq, const float* __restrict__ bk,
                         const float* __restrict__ bv, const float* __restrict__ bsk,
                         __hip_bfloat16* __restrict__ B3t, float* __restrict__ bias3)
{
    int idx = blockIdx.x*256 + threadIdx.x;         // n*256 + k, n<1024
    if (idx >= 1024*256) return;
    int n = idx / 256, k = idx % 256;
    int g = n >> 8, nn = n & 255;
    const float* W = (g==0)?Wq:(g==1)?Wk:(g==2)?Wv:Wsk;
    B3t[idx] = f2bf(W[k*256 + nn]);
    if (k == 0) {
        const float* B = (g==0)?bq:(g==1)?bk:(g==2)?bv:bsk;
        bias3[n] = B[nn];
    }
}

// generic fp32 -> bf16 elementwise convert (layout-preserving)
__global__ void cvt_f32_bf16(const float* __restrict__ in, __hip_bfloat16* __restrict__ out, int n)
{
    int i = blockIdx.x*256 + threadIdx.x;
    if (i < n) out[i] = f2bf(in[i]);
}

// ---------------- RGCN aggregation: one WAVE per (node,rel) key, unroll-4 ILP ----------------
__global__ __launch_bounds__(256) void agg1_kernel(const float* __restrict__ x,
                                                   const int* __restrict__ row_ptr,
                                                   const int* __restrict__ csr_src,
                                                   __hip_bfloat16* __restrict__ A1)
{
    int b = blockIdx.x*4 + (threadIdx.x >> 6);   // key = i*4 + r
    int lane = threadIdx.x & 63;
    int i = b >> 2, r = b & 3;
    int e0 = row_ptr[b], e1 = row_ptr[b+1];
    float sx0=0.f,sy0=0.f, sx1=0.f,sy1=0.f, sx2=0.f,sy2=0.f, sx3=0.f,sy3=0.f;
    int e = e0;
    for (; e+4 <= e1; e += 4) {
        int i0=csr_src[e], i1=csr_src[e+1], i2=csr_src[e+2], i3=csr_src[e+3];
        float2 v0 = *(const float2*)(x + (size_t)i0*IN_F + lane*2);
        float2 v1 = *(const float2*)(x + (size_t)i1*IN_F + lane*2);
        float2 v2 = *(const float2*)(x + (size_t)i2*IN_F + lane*2);
        float2 v3 = *(const float2*)(x + (size_t)i3*IN_F + lane*2);
        sx0+=v0.x; sy0+=v0.y; sx1+=v1.x; sy1+=v1.y;
        sx2+=v2.x; sy2+=v2.y; sx3+=v3.x; sy3+=v3.y;
    }
    for (; e < e1; e++) {
        int i0 = csr_src[e];
        float2 v = *(const float2*)(x + (size_t)i0*IN_F + lane*2);
        sx0+=v.x; sy0+=v.y;
    }
    float sx = (sx0+sx1)+(sx2+sx3);
    float sy = (sy0+sy1)+(sy2+sy3);
    float inv = (e1>e0) ? 1.f/(float)(e1-e0) : 0.f;
    *(unsigned*)(A1 + (size_t)i*640 + 128 + r*128 + lane*2) = pack_bf2(sx*inv, sy*inv);
    if (r == 0) {
        float2 v = *(const float2*)(x + (size_t)i*IN_F + lane*2);
        *(unsigned*)(A1 + (size_t)i*640 + lane*2) = pack_bf2(v.x, v.y);
    }
}

__global__ __launch_bounds__(256) void agg2_kernel(const int* __restrict__ row_ptr,
                                                   const int* __restrict__ csr_src,
                                                   __hip_bfloat16* __restrict__ A2)
{
    int b = blockIdx.x*4 + (threadIdx.x >> 6);
    int lane = threadIdx.x & 63;
    int i = b >> 2, r = b & 3;
    int e0 = row_ptr[b], e1 = row_ptr[b+1];
    float a0=0.f,a1=0.f,a2=0.f,a3=0.f;
    float b0=0.f,b1=0.f,b2=0.f,b3=0.f;
    float c0=0.f,c1=0.f,c2=0.f,c3=0.f;
    float d0=0.f,d1=0.f,d2=0.f,d3=0.f;
    int e = e0;
    for (; e+4 <= e1; e += 4) {
        int i0=csr_src[e], i1=csr_src[e+1], i2=csr_src[e+2], i3=csr_src[e+3];
        ushort4 u0 = *(const ushort4*)(A2 + (size_t)i0*1280 + lane*4);
        ushort4 u1 = *(const ushort4*)(A2 + (size_t)i1*1280 + lane*4);
        ushort4 u2 = *(const ushort4*)(A2 + (size_t)i2*1280 + lane*4);
        ushort4 u3 = *(const ushort4*)(A2 + (size_t)i3*1280 + lane*4);
        a0+=bfbits2f(u0.x); a1+=bfbits2f(u0.y); a2+=bfbits2f(u0.z); a3+=bfbits2f(u0.w);
        b0+=bfbits2f(u1.x); b1+=bfbits2f(u1.y); b2+=bfbits2f(u1.z); b3+=bfbits2f(u1.w);
        c0+=bfbits2f(u2.x); c1+=bfbits2f(u2.y); c2+=bfbits2f(u2.z); c3+=bfbits2f(u2.w);
        d0+=bfbits2f(u3.x); d1+=bfbits2f(u3.y); d2+=bfbits2f(u3.z); d3+=bfbits2f(u3.w);
    }
    for (; e < e1; e++) {
        int i0 = csr_src[e];
        ushort4 u = *(const ushort4*)(A2 + (size_t)i0*1280 + lane*4);
        a0+=bfbits2f(u.x); a1+=bfbits2f(u.y); a2+=bfbits2f(u.z); a3+=bfbits2f(u.w);
    }
    float s0=(a0+b0)+(c0+d0), s1=(a1+b1)+(c1+d1), s2=(a2+b2)+(c2+d2), s3=(a3+b3)+(c3+d3);
    float inv = (e1>e0) ? 1.f/(float)(e1-e0) : 0.f;
    uint2 w;
    w.x = pack_bf2(s0*inv, s1*inv);
    w.y = pack_bf2(s2*inv, s3*inv);
    *(uint2*)(A2 + (size_t)i*1280 + 256 + r*256 + lane*4) = w;
}

// ---------------- LDS-pipelined GEMM (r2 config: best measured) ----------------
// Triple-buffered global_load_lds, 2 batches in flight, counted vmcnt(L).
// Chunk-XOR LDS swizzle via pre-swizzled global source (0 bank conflicts, r1).
template<int MI>
__device__ __forceinline__ void gemm_bt_body(const __hip_bfloat16* __restrict__ A, int lda,
                                             const __hip_bfloat16* __restrict__ Bt,
                                             const float* __restrict__ bias,
                                             __hip_bfloat16* __restrict__ C, int ldc,
                                             int M, int K, int relu,
                                             int tile_m, int tile_n,
                                             __hip_bfloat16* lds_a, __hip_bfloat16* lds_b)
{
    constexpr int A_ELEMS = MI*1024;
    constexpr int B_ELEMS = 4096;
    constexpr int L = MI/2 + 2;
    const int tid  = threadIdx.x;
    const int wave = tid >> 6;
    const int lane = tid & 63;
    const int wm = wave >> 1, wn = wave & 1;
    const int fm = lane & 15;
    const int q  = lane >> 4;
    const int sw = (q ^ ((fm >> 1) & 3)) * 8;

    floatx4 acc[MI][4];
    #pragma unroll
    for (int i=0;i<MI;i++)
        #pragma unroll
        for (int j=0;j<4;j++) acc[i][j] = (floatx4){0.f,0.f,0.f,0.f};

    const int srow   = lane >> 2;
    const int schunk = lane & 3;
    size_t a_goff[MI/2];
    #pragma unroll
    for (int s = 0; s < MI/2; ++s) {
        int r = (s*4 + wave)*16 + srow;
        int c = schunk ^ ((r >> 1) & 3);
        a_goff[s] = (size_t)min(tile_m + r, M-1)*lda + c*8;
    }
    size_t b_goff[2];
    #pragma unroll
    for (int s = 0; s < 2; ++s) {
        int r = (s*4 + wave)*16 + srow;
        int c = schunk ^ ((r >> 1) & 3);
        b_goff[s] = (size_t)(tile_n + r)*K + c*8;
    }

    const int nt = K >> 5;

    auto issue = [&](int t, int bufi) {
        const int kn = t << 5;
        #pragma unroll
        for (int s = 0; s < MI/2; ++s)
            gload_lds16(A + a_goff[s] + kn, lds_a + bufi*A_ELEMS + (s*4 + wave)*512);
        #pragma unroll
        for (int s = 0; s < 2; ++s)
            gload_lds16(Bt + b_goff[s] + kn, lds_b + bufi*B_ELEMS + (s*4 + wave)*512);
    };

    issue(0, 0);
    if (nt > 1) { issue(1, 1); wait_vm<L>(); }
    else        { wait_vm<0>(); }
    __builtin_amdgcn_s_barrier();

    int cur = 0, nx2 = 2;
    for (int t = 0; t < nt; ++t) {
        if (t + 2 < nt) issue(t + 2, nx2);

        const __hip_bfloat16* la = lds_a + cur*A_ELEMS;
        const __hip_bfloat16* lb = lds_b + cur*B_ELEMS;
        short8 afr[MI], bfr[4];
        #pragma unroll
        for (int i=0;i<MI;i++)
            afr[i] = *(const short8*)(la + (wm*(MI*16) + i*16 + fm)*32 + sw);
        #pragma unroll
        for (int j=0;j<4;j++)
            bfr[j] = *(const short8*)(lb + (wn*64 + j*16 + fm)*32 + sw);

        __builtin_amdgcn_s_setprio(1);
        #pragma unroll
        for (int i=0;i<MI;i++)
            #pragma unroll
            for (int j=0;j<4;j++)
                acc[i][j] = __builtin_amdgcn_mfma_f32_16x16x32_bf16(afr[i], bfr[j], acc[i][j], 0,0,0);
        __builtin_amdgcn_s_setprio(0);

        if (t + 1 < nt) {
            if (t + 2 < nt) wait_vm<L>();
            else            wait_vm<0>();
            __builtin_amdgcn_s_barrier();
            cur = (cur == 2) ? 0 : cur + 1;
            nx2 = (nx2 == 2) ? 0 : nx2 + 1;
        }
    }

    const int crow_base = tile_m + wm*(MI*16);
    const int ccol_base = tile_n + wn*64;
    #pragma unroll
    for (int i=0;i<MI;i++) {
        #pragma unroll
        for (int j=0;j<4;j++) {
            int c  = ccol_base + j*16 + fm;
            float bb = bias[c];
            #pragma unroll
            for (int rg=0; rg<4; rg++) {
                int r = crow_base + i*16 + q*4 + rg;
                if (r < M) {
                    float v = acc[i][j][rg] + bb;
                    if (relu) v = fmaxf(v, 0.f);
                    C[(size_t)r*ldc + c] = f2bf(v);
                }
            }
        }
    }
}

template<int MI>
__global__ __launch_bounds__(256) void gemm_bt_t(const __hip_bfloat16* __restrict__ A, int lda,
                                                 const __hip_bfloat16* __restrict__ Bt,
                                                 const float* __restrict__ bias,
                                                 __hip_bfloat16* __restrict__ C, int ldc,
                                                 int M, int K, int relu)
{
    __shared__ __align__(16) __hip_bfloat16 lds_a[3*MI*1024];
    __shared__ __align__(16) __hip_bfloat16 lds_b[3*4096];
    int2 xy = xcd_swizzle();
    gemm_bt_body<MI>(A, lda, Bt, bias, C, ldc, M, K, relu,
                     xy.x*(MI*32), xy.y*128, lds_a, lds_b);
}

// ---------------- fused GRU gate-GEMM + elementwise (NEW, r5) ----------------
// Replaces gemm_bt_dual (61 MB gi/gh write) + gru_kernel (81 MB read + 20 MB
// write) with ONE kernel writing only the 20 MB fp32 output: block = 64 rows x
// 32 channels, computing ALL SIX gate tiles (gi r/z/n from hatt@W_ih^T, gh
// r/z/n from hprev@W_hh^T) in one K-loop. Per K-step staging: A 2x64 rows +
// B 6x32 rows (gate*256+c0+ri) = 20 KB; triple-buffered = 60 KB -> 2 blocks/CU.
// Each wave owns 16 rows x BOTH mats (12 MFMA/step), so its epilogue has gi AND
// gh for the same elements -> GRU math local, no cross-wave exchange.
// Same r2 pipeline skeleton: 2 batches in flight, vmcnt(5), chunk-XOR swizzle
// (all frag row bases are multiples of 16 -> XOR key (row>>1)&3 == (fm>>1)&3).
__global__ __launch_bounds__(256) void gemm_gru_fused(
    const __hip_bfloat16* __restrict__ A0,   // hatt bf16 [N,256]
    const __hip_bfloat16* __restrict__ A1,   // hprev bf16 [N,256]
    const __hip_bfloat16* __restrict__ Bt0,  // W_ih [768][256]
    const __hip_bfloat16* __restrict__ Bt1,  // W_hh [768][256]
    const float* __restrict__ b_ih, const float* __restrict__ b_hh,
    const float* __restrict__ hprev, float* __restrict__ out)
{
    constexpr int BUF_ELEMS = 10240;  // A 128x32 (4096) + B 192x32 (6144)
    __shared__ __align__(16) __hip_bfloat16 lds[3*BUF_ELEMS];   // 60 KB
    int2 xy = xcd_swizzle();          // grid (313, 8), y = channel chunk
    const int tile_m = xy.x * 64;
    const int c0     = xy.y * 32;
    const int tid = threadIdx.x, wave = tid >> 6, lane = tid & 63;
    const int fm = lane & 15, q = lane >> 4;
    const int sw = (q ^ ((fm >> 1) & 3)) * 8;

    // 20 staging segments (1 KB = 16 rows x 64 B each): 0..7 A, 8..19 B; 5/wave.
    const int sub = lane >> 2, ch = lane & 3;
    const __hip_bfloat16* gsrc[5];
    int dstoff[5];
    #pragma unroll
    for (int s = 0; s < 5; ++s) {
        int seg = wave*5 + s;
        if (seg < 8) {
            int fr = seg*16 + sub;                   // 0..127
            int mat = fr >> 6, rl = fr & 63;
            int c = ch ^ ((fr >> 1) & 3);
            int grow = min(tile_m + rl, N_NODES-1);
            gsrc[s] = (mat ? A1 : A0) + (size_t)grow*256 + c*8;
            dstoff[s] = seg*512;
        } else {
            int fs = seg - 8;
            int fr = fs*16 + sub;                    // 0..191
            int grp = fr >> 5, ri = fr & 31;         // grp = mat*3 + gate
            int mat = grp >= 3, gate = mat ? grp-3 : grp;
            int c = ch ^ ((fr >> 1) & 3);
            int grow = gate*256 + c0 + ri;
            gsrc[s] = (mat ? Bt1 : Bt0) + (size_t)grow*256 + c*8;
            dstoff[s] = 4096 + fs*512;
        }
    }

    floatx4 acc[2][3][2];
    #pragma unroll
    for (int m=0;m<2;m++)
        #pragma unroll
        for (int g=0;g<3;g++)
            #pragma unroll
            for (int f=0;f<2;f++) acc[m][g][f] = (floatx4){0.f,0.f,0.f,0.f};

    auto issue = [&](int t, int bufi) {
        const int kn = t << 5;
        #pragma unroll
        for (int s = 0; s < 5; ++s)
            gload_lds16(gsrc[s] + kn, lds + bufi*BUF_ELEMS + dstoff[s]);
    };

    issue(0, 0);
    issue(1, 1);
    wait_vm<5>();
    __builtin_amdgcn_s_barrier();

    int cur = 0, nx2 = 2;
    #pragma unroll 1
    for (int t = 0; t < 8; ++t) {
        if (t + 2 < 8) issue(t + 2, nx2);

        const __hip_bfloat16* lb = lds + cur*BUF_ELEMS;
        short8 af[2], bf_[2][3][2];
        #pragma unroll
        for (int m=0;m<2;m++)
            af[m] = *(const short8*)(lb + (m*64 + wave*16 + fm)*32 + sw);
        #pragma unroll
        for (int m=0;m<2;m++)
            #pragma unroll
            for (int g=0;g<3;g++)
                #pragma unroll
                for (int f=0;f<2;f++)
                    bf_[m][g][f] = *(const short8*)(lb + 4096 + (((m*3+g)*32) + f*16 + fm)*32 + sw);

        __builtin_amdgcn_s_setprio(1);
        #pragma unroll
        for (int m=0;m<2;m++)
            #pragma unroll
            for (int g=0;g<3;g++)
                #pragma unroll
                for (int f=0;f<2;f++)
                    acc[m][g][f] = __builtin_amdgcn_mfma_f32_16x16x32_bf16(af[m], bf_[m][g][f], acc[m][g][f], 0,0,0);
        __builtin_amdgcn_s_setprio(0);

        if (t + 1 < 8) {
            if (t + 2 < 8) wait_vm<5>();
            else           wait_vm<0>();
            __builtin_amdgcn_s_barrier();
            cur = (cur == 2) ? 0 : cur + 1;
            nx2 = (nx2 == 2) ? 0 : nx2 + 1;
        }
    }

    // epilogue: GRU math, write fp32 out only
    #pragma unroll
    for (int f=0; f<2; ++f) {
        int c = c0 + f*16 + fm;
        float bir = b_ih[c], biz = b_ih[256+c], bin = b_ih[512+c];
        float bhr = b_hh[c], bhz = b_hh[256+c], bhn = b_hh[512+c];
        #pragma unroll
        for (int rg=0; rg<4; ++rg) {
            int r = tile_m + wave*16 + q*4 + rg;
            if (r < N_NODES) {
                float gir = acc[0][0][f][rg] + bir;
                float giz = acc[0][1][f][rg] + biz;
                float gin = acc[0][2][f][rg] + bin;
                float ghr = acc[1][0][f][rg] + bhr;
                float ghz = acc[1][1][f][rg] + bhz;
                float ghn = acc[1][2][f][rg] + bhn;
                float rr = 1.f/(1.f + __expf(-(gir + ghr)));
                float zz = 1.f/(1.f + __expf(-(giz + ghz)));
                float nn = tanhf(gin + rr*ghn);
                float h  = hprev[(size_t)r*256 + c];
                out[(size_t)r*256 + c] = (1.f - zz)*nn + zz*h;
            }
        }
    }
}

// ---------------- attention scores: ONE WAVE PER NODE ----------------
__global__ __launch_bounds__(256) void score_kernel(const __hip_bfloat16* __restrict__ qkvs,
                                                    const int* __restrict__ row_ptr,
                                                    const int* __restrict__ csr_src,
                                                    float* __restrict__ score)
{
    int i = blockIdx.x*4 + (threadIdx.x >> 6);
    int lane = threadIdx.x & 63;
    int h = lane >> 4, d4 = lane & 15;
    int e0 = row_ptr[i*R_REL], e1 = row_ptr[i*R_REL + R_REL];
    ushort4 qv = *(const ushort4*)(qkvs + (size_t)i*1024 + lane*4);
    float qx=bfbits2f(qv.x), qy=bfbits2f(qv.y), qz=bfbits2f(qv.z), qw=bfbits2f(qv.w);
    float* sp = score + (size_t)h*E_EDGES;
    int j = e0;
    for (; j+2 <= e1; j += 2) {
        int s0 = csr_src[j], s1 = csr_src[j+1];
        ushort4 k0 = *(const ushort4*)(qkvs + (size_t)s0*1024 + 256 + lane*4);
        ushort4 k1 = *(const ushort4*)(qkvs + (size_t)s1*1024 + 256 + lane*4);
        float d0 = qx*bfbits2f(k0.x)+qy*bfbits2f(k0.y)+qz*bfbits2f(k0.z)+qw*bfbits2f(k0.w);
        float d1 = qx*bfbits2f(k1.x)+qy*bfbits2f(k1.y)+qz*bfbits2f(k1.z)+qw*bfbits2f(k1.w);
        #pragma unroll
        for (int o=1;o<16;o<<=1){ d0 += __shfl_xor(d0,o,64); d1 += __shfl_xor(d1,o,64); }
        if (d4 == 0) { sp[j] = d0*0.125f; sp[j+1] = d1*0.125f; }
    }
    for (; j < e1; j++) {
        int s0 = csr_src[j];
        ushort4 k0 = *(const ushort4*)(qkvs + (size_t)s0*1024 + 256 + lane*4);
        float d0 = qx*bfbits2f(k0.x)+qy*bfbits2f(k0.y)+qz*bfbits2f(k0.z)+qw*bfbits2f(k0.w);
        #pragma unroll
        for (int o=1;o<16;o<<=1) d0 += __shfl_xor(d0,o,64);
        if (d4 == 0) sp[j] = d0*0.125f;
    }
}

// ---------------- attention aggregate: ONE WAVE PER NODE, all 4 heads ----------------
__global__ __launch_bounds__(256) void attn_agg_kernel(const __hip_bfloat16* __restrict__ qkvs,
                                                       const float* __restrict__ score,
                                                       const int* __restrict__ row_ptr,
                                                       const int* __restrict__ csr_src,
                                                       __hip_bfloat16* __restrict__ hatt)
{
    int i = blockIdx.x*4 + (threadIdx.x >> 6);   // node (4 nodes per block)
    int lane = threadIdx.x & 63;
    int h  = lane >> 4;
    int d4 = lane & 15;
    int e0 = row_ptr[i*R_REL], e1 = row_ptr[i*R_REL + R_REL];
    int deg = e1 - e0;
    const float* sp = score + (size_t)h*E_EDGES + e0;

    float m = -1e30f;
    for (int j = d4; j < deg; j += 16) m = fmaxf(m, sp[j]);
    #pragma unroll
    for (int o=1;o<16;o<<=1) m = fmaxf(m, __shfl_xor(m, o, 64));

    float ssum = 0.f;
    for (int j = d4; j < deg; j += 16) ssum += __expf(sp[j] - m);
    #pragma unroll
    for (int o=1;o<16;o<<=1) ssum += __shfl_xor(ssum, o, 64);
    float inv = 1.f / fmaxf(ssum, 1e-16f);

    float ax=0.f, ay=0.f, az=0.f, aw=0.f;
    int j = 0;
    for (; j+4 <= deg; j += 4) {
        int s0=csr_src[e0+j], s1=csr_src[e0+j+1], s2=csr_src[e0+j+2], s3=csr_src[e0+j+3];
        float w0 = __expf(sp[j]   - m) * inv;
        float w1 = __expf(sp[j+1] - m) * inv;
        float w2 = __expf(sp[j+2] - m) * inv;
        float w3 = __expf(sp[j+3] - m) * inv;
        ushort4 u0 = *(const ushort4*)(qkvs + (size_t)s0*1024 + 512 + lane*4);
        ushort4 u1 = *(const ushort4*)(qkvs + (size_t)s1*1024 + 512 + lane*4);
        ushort4 u2 = *(const ushort4*)(qkvs + (size_t)s2*1024 + 512 + lane*4);
        ushort4 u3 = *(const ushort4*)(qkvs + (size_t)s3*1024 + 512 + lane*4);
        ax += w0*bfbits2f(u0.x) + w1*bfbits2f(u1.x) + w2*bfbits2f(u2.x) + w3*bfbits2f(u3.x);
        ay += w0*bfbits2f(u0.y) + w1*bfbits2f(u1.y) + w2*bfbits2f(u2.y) + w3*bfbits2f(u3.y);
        az += w0*bfbits2f(u0.z) + w1*bfbits2f(u1.z) + w2*bfbits2f(u2.z) + w3*bfbits2f(u3.z);
        aw += w0*bfbits2f(u0.w) + w1*bfbits2f(u1.w) + w2*bfbits2f(u2.w) + w3*bfbits2f(u3.w);
    }
    for (; j < deg; j++) {
        int s = csr_src[e0+j];
        float w = __expf(sp[j] - m) * inv;
        ushort4 u = *(const ushort4*)(qkvs + (size_t)s*1024 + 512 + lane*4);
        ax += w*bfbits2f(u.x); ay += w*bfbits2f(u.y);
        az += w*bfbits2f(u.z); aw += w*bfbits2f(u.w);
    }
    ushort4 sk = *(const ushort4*)(qkvs + (size_t)i*1024 + 768 + lane*4);
    uint2 w;
    w.x = pack_bf2(ax + bfbits2f(sk.x), ay + bfbits2f(sk.y));
    w.y = pack_bf2(az + bfbits2f(sk.z), aw + bfbits2f(sk.w));
    *(uint2*)(hatt + (size_t)i*256 + lane*4) = w;
}

// ---------------- launch ----------------
extern "C" void kernel_launch(void* const* d_in, const int* in_sizes, int n_in,
                              void* d_out, int out_size, void* d_ws, size_t ws_size,
                              hipStream_t stream)
{
    const float* x       = (const float*)d_in[0];
    const int* edge_index= (const int*)d_in[1];
    const int* edge_type = (const int*)d_in[2];
    const float* hprev   = (const float*)d_in[3];
    const float* W1      = (const float*)d_in[4];
    const float* root1   = (const float*)d_in[5];
    const float* b1      = (const float*)d_in[6];
    const float* W2      = (const float*)d_in[7];
    const float* root2   = (const float*)d_in[8];
    const float* b2      = (const float*)d_in[9];
    const float* Wq      = (const float*)d_in[10];
    const float* bq      = (const float*)d_in[11];
    const float* Wk      = (const float*)d_in[12];
    const float* bk      = (const float*)d_in[13];
    const float* Wv      = (const float*)d_in[14];
    const float* bv      = (const float*)d_in[15];
    const float* Wskip   = (const float*)d_in[16];
    const float* bskip   = (const float*)d_in[17];
    const float* W_ih    = (const float*)d_in[18];
    const float* b_ih    = (const float*)d_in[19];
    const float* W_hh    = (const float*)d_in[20];
    const float* b_hh    = (const float*)d_in[21];

    char* ws = (char*)d_ws;
    size_t off = 0;
    auto take = [&](size_t bytes)->char* {
        char* p = ws + off;
        off = (off + bytes + 255) & ~(size_t)255;
        return p;
    };
    int* cnt        = (int*)take((size_t)NRKEYS*4);
    int* row_ptr    = (int*)take((size_t)(NRKEYS+1)*4);
    int* cursor     = (int*)take((size_t)NRKEYS*4);
    int* csr_src    = (int*)take((size_t)E_EDGES*4);
    int* blocksum   = (int*)take((size_t)SCAN_BLOCKS*4);
    int* blockoff   = (int*)take((size_t)(SCAN_BLOCKS+1)*4);
    float* score    = (float*)take((size_t)R_REL*E_EDGES*4);
    __hip_bfloat16* B1t   = (__hip_bfloat16*)take((size_t)256*640*2);
    __hip_bfloat16* B2t   = (__hip_bfloat16*)take((size_t)256*1280*2);
    __hip_bfloat16* B3t   = (__hip_bfloat16*)take((size_t)1024*256*2);
    __hip_bfloat16* Biht  = (__hip_bfloat16*)take((size_t)768*256*2);
    __hip_bfloat16* Bhht  = (__hip_bfloat16*)take((size_t)768*256*2);
    float*          bias3 = (float*)take((size_t)1024*4);
    __hip_bfloat16* hprev_bf = (__hip_bfloat16*)take((size_t)N_NODES*256*2);
    char* P1 = take((size_t)N_NODES*640*2);
    char* P2 = take((size_t)N_NODES*1536*2);

    __hip_bfloat16* A1   = (__hip_bfloat16*)P1;   // [N,640]  dead after gemm1
    __hip_bfloat16* h2   = (__hip_bfloat16*)P1;   // [N,256]  dead after gemm3
    __hip_bfloat16* hatt = (__hip_bfloat16*)P1;   // [N,256]  read by fused GRU
    __hip_bfloat16* A2   = (__hip_bfloat16*)P2;   // [N,1280] dead after gemm2
    __hip_bfloat16* qkvs = (__hip_bfloat16*)P2;   // [N,1024] dead after attn_agg

    hipMemsetAsync(cnt, 0, (size_t)NRKEYS*4, stream);
    count_kernel<<<(E_EDGES+255)/256, 256, 0, stream>>>(edge_index, edge_type, cnt);
    scan_reduce_kernel<<<SCAN_BLOCKS, 1024, 0, stream>>>(cnt, blocksum);
    scan_sums_kernel<<<1, 128, 0, stream>>>(blocksum, blockoff);
    scan_apply_kernel<<<SCAN_BLOCKS, 1024, 0, stream>>>(cnt, blockoff, row_ptr, cursor);
    fill_kernel<<<(E_EDGES+255)/256, 256, 0, stream>>>(edge_index, edge_type, cursor, csr_src);

    make_b1t<<<(256*640+255)/256, 256, 0, stream>>>(root1, W1, B1t);
    make_b2t<<<(256*1280+255)/256, 256, 0, stream>>>(root2, W2, B2t);
    make_b3t<<<(1024*256+255)/256, 256, 0, stream>>>(Wq, Wk, Wv, Wskip, bq, bk, bv, bskip, B3t, bias3);
    cvt_f32_bf16<<<(768*256+255)/256, 256, 0, stream>>>(W_ih, Biht, 768*256);
    cvt_f32_bf16<<<(768*256+255)/256, 256, 0, stream>>>(W_hh, Bhht, 768*256);
    cvt_f32_bf16<<<(N_NODES*256+255)/256, 256, 0, stream>>>(hprev, hprev_bf, N_NODES*256);

    agg1_kernel<<<NRKEYS/4, 256, 0, stream>>>(x, row_ptr, csr_src, A1);

    // h1 = relu(A1 * B1) written into A2 cols 0..255 (ldc=1280)
    dim3 g12(313, 2);
    gemm_bt_t<2><<<g12, 256, 0, stream>>>(A1, 640, B1t, b1, A2, 1280, N_NODES, 640, 1);

    agg2_kernel<<<NRKEYS/4, 256, 0, stream>>>(row_ptr, csr_src, A2);

    // h2 overwrites A1 (dead) in P1
    gemm_bt_t<2><<<g12, 256, 0, stream>>>(A2, 1280, B2t, b2, h2, 256, N_NODES, 1280, 1);

    // qkvs overwrites A2 (dead) in P2
    dim3 g3(157, 8);
    gemm_bt_t<4><<<g3, 256, 0, stream>>>(h2, 256, B3t, bias3, qkvs, 1024, N_NODES, 256, 0);

    score_kernel<<<N_NODES/4, 256, 0, stream>>>(qkvs, row_ptr, csr_src, score);
    attn_agg_kernel<<<N_NODES/4, 256, 0, stream>>>(qkvs, score, row_ptr, csr_src, hatt);

    // fused GRU gate-GEMMs + elementwise: writes fp32 out directly
    gemm_gru_fused<<<dim3(313, 8), 256, 0, stream>>>(hatt, hprev_bf, Biht, Bhht,
                                                     b_ih, b_hh, hprev, (float*)d_out);
}

// Round 6
// 426.350 us; speedup vs baseline: 1.1431x; 1.0113x over previous
//
#include <hip/hip_runtime.h>
#include <hip/hip_bf16.h>
#include <stdint.h>

#define N_NODES 20000
#define E_EDGES 320000
#define IN_F    128
#define HIDF    256
#define R_REL   4
#define NRKEYS  (N_NODES*R_REL)   // 80000
#define SCAN_BLOCKS 80            // 80*1024 = 81920 >= NRKEYS

typedef __attribute__((ext_vector_type(8))) short  short8;
typedef __attribute__((ext_vector_type(4))) float  floatx4;

__device__ __forceinline__ float bf2f(__hip_bfloat16 v){ return __bfloat162float(v); }
__device__ __forceinline__ __hip_bfloat16 f2bf(float v){ return __float2bfloat16(v); }
__device__ __forceinline__ float bfbits2f(unsigned short u){ return __uint_as_float(((unsigned)u)<<16); }
__device__ __forceinline__ unsigned short f2bfbits(float v){
    __hip_bfloat16 h = __float2bfloat16(v);
    return *(unsigned short*)&h;
}
__device__ __forceinline__ unsigned pack_bf2(float a, float b){
    return (unsigned)f2bfbits(a) | ((unsigned)f2bfbits(b) << 16);
}

// async global->LDS, 16B per lane. LDS dest is WAVE-UNIFORM base (+lane*16 by HW);
// global src is per-lane (pre-swizzled to implement the LDS XOR layout).
__device__ __forceinline__ void gload_lds16(const void* g, void* l)
{
    __builtin_amdgcn_global_load_lds((const __attribute__((address_space(1))) void*)g,
                                     (__attribute__((address_space(3))) void*)l, 16, 0, 0);
}

template<int N>
__device__ __forceinline__ void wait_vm()
{
    if constexpr (N == 0)      asm volatile("s_waitcnt vmcnt(0)" ::: "memory");
    else if constexpr (N == 3) asm volatile("s_waitcnt vmcnt(3)" ::: "memory");
    else if constexpr (N == 4) asm volatile("s_waitcnt vmcnt(4)" ::: "memory");
    else if constexpr (N == 5) asm volatile("s_waitcnt vmcnt(5)" ::: "memory");
    else if constexpr (N == 8) asm volatile("s_waitcnt vmcnt(8)" ::: "memory");
    else                       asm volatile("s_waitcnt vmcnt(0)" ::: "memory");
}

// bijective XCD-chunked swizzle (m204 formula): blocks remapped so each XCD owns a
// contiguous j-range; decomposing j with y FASTEST puts all column-tiles of the
// same A-panel on the SAME XCD back-to-back -> A-panel read from HBM once, then
// L2-hits instead of L3/HBM for the other y's. (Verified r2: FETCH 63.6->17.3 MB.)
// GEMM-structure history: r3 quad-buffer depth-3 lost to occupancy (LDS 64K -> 2
// blk/CU); r4 no-LDS register GEMM lost to per-wave L2 latency (MfmaUtil 7.6%).
// The r2 triple-buffer / 2-in-flight / vmcnt(L) structure is the measured optimum.
__device__ __forceinline__ int2 xcd_swizzle()
{
    int gx = gridDim.x, gy = gridDim.y;
    int nwg = gx * gy;
    int lin = blockIdx.x + gx * blockIdx.y;
    int q = nwg >> 3, r = nwg & 7;
    int k = lin & 7, i = lin >> 3;
    int j = (k < r ? k*(q+1) : r*(q+1) + (k-r)*q) + i;
    return make_int2(j / gy, j % gy);   // (x tile, y tile), y fastest
}

// ---------------- CSR build ----------------
__global__ void count_kernel(const int* __restrict__ ei, const int* __restrict__ et,
                             int* __restrict__ cnt)
{
    int e = blockIdx.x*256 + threadIdx.x;
    if (e >= E_EDGES) return;
    int dst = ei[E_EDGES + e];
    atomicAdd(&cnt[dst*R_REL + et[e]], 1);
}

// 3-phase parallel exclusive scan over cnt[NRKEYS] -> row_ptr, cursor
__global__ __launch_bounds__(1024) void scan_reduce_kernel(const int* __restrict__ cnt,
                                                           int* __restrict__ blocksum)
{
    int ix = blockIdx.x*1024 + threadIdx.x;
    int v = (ix < NRKEYS) ? cnt[ix] : 0;
    #pragma unroll
    for (int o=32;o>0;o>>=1) v += __shfl_xor(v, o, 64);
    __shared__ int wsum[16];
    int wave = threadIdx.x >> 6, lane = threadIdx.x & 63;
    if (lane == 0) wsum[wave] = v;
    __syncthreads();
    if (threadIdx.x == 0) {
        int s = 0;
        #pragma unroll
        for (int w=0;w<16;w++) s += wsum[w];
        blocksum[blockIdx.x] = s;
    }
}

__global__ __launch_bounds__(128) void scan_sums_kernel(const int* __restrict__ blocksum,
                                                        int* __restrict__ blockoff)
{
    __shared__ int s[128];
    int t = threadIdx.x;
    int v = (t < SCAN_BLOCKS) ? blocksum[t] : 0;
    s[t] = v; __syncthreads();
    for (int off=1; off<128; off<<=1) {
        int u = (t>=off) ? s[t-off] : 0;
        __syncthreads();
        s[t] += u;
        __syncthreads();
    }
    if (t < SCAN_BLOCKS) blockoff[t] = s[t] - v;   // exclusive
}

__global__ __launch_bounds__(1024) void scan_apply_kernel(const int* __restrict__ cnt,
                                                          const int* __restrict__ blockoff,
                                                          int* __restrict__ row_ptr,
                                                          int* __restrict__ cursor)
{
    __shared__ int s[1024];
    int t = threadIdx.x;
    int ix = blockIdx.x*1024 + t;
    int v = (ix < NRKEYS) ? cnt[ix] : 0;
    s[t] = v; __syncthreads();
    for (int off=1; off<1024; off<<=1) {
        int u = (t>=off) ? s[t-off] : 0;
        __syncthreads();
        s[t] += u;
        __syncthreads();
    }
    if (ix < NRKEYS) {
        int excl = blockoff[blockIdx.x] + s[t] - v;
        row_ptr[ix] = excl;
        cursor[ix]  = excl;
        if (ix == NRKEYS-1) row_ptr[NRKEYS] = excl + v;
    }
}

__global__ void fill_kernel(const int* __restrict__ ei, const int* __restrict__ et,
                            int* __restrict__ cursor, int* __restrict__ csr_src)
{
    int e = blockIdx.x*256 + threadIdx.x;
    if (e >= E_EDGES) return;
    int src = ei[e];
    int dst = ei[E_EDGES + e];
    int key = dst*R_REL + et[e];
    int pos = atomicAdd(&cursor[key], 1);
    csr_src[pos] = src;
}

// ---------------- weight prep: fp32 sources -> bf16 B^T = [Nout][K] ----------------
__global__ void make_b1t(const float* __restrict__ root1,
                         const float* __restrict__ W1,
                         __hip_bfloat16* __restrict__ B1t)
{
    int idx = blockIdx.x*256 + threadIdx.x;         // n*640 + k
    if (idx >= 256*640) return;
    int n = idx / 640, k = idx % 640;
    float v;
    if (k < 128) v = root1[k*256 + n];
    else         v = W1[(k-128)*256 + n];           // W1 contiguous [R*128][256]
    B1t[idx] = f2bf(v);
}

__global__ void make_b2t(const float* __restrict__ root2,
                         const float* __restrict__ W2,
                         __hip_bfloat16* __restrict__ B2t)
{
    int idx = blockIdx.x*256 + threadIdx.x;         // n*1280 + k
    if (idx >= 256*1280) return;
    int n = idx / 1280, k = idx % 1280;
    float v;
    if (k < 256) v = root2[k*256 + n];
    else         v = W2[(k-256)*256 + n];           // W2 contiguous [R*256][256]
    B2t[idx] = f2bf(v);
}

__global__ void make_b3t(const float* __restrict__ Wq, const float* __restrict__ Wk,
                         const float* __restrict__ Wv, const float* __restrict__ Wsk,
                         const float* __restrict__ bq, const float* __restrict__ bk,
                         const float* __restrict__ bv, const float* __restrict__ bsk,
                         __hip_bfloat16* __restrict__ B3t, float* __restrict__ bias3)
{
    int idx = blockIdx.x*256 + threadIdx.x;         // n*256 + k, n<1024
    if (idx >= 1024*256) return;
    int n = idx / 256, k = idx % 256;
    int g = n >> 8, nn = n & 255;
    const float* W = (g==0)?Wq:(g==1)?Wk:(g==2)?Wv:Wsk;
    B3t[idx] = f2bf(W[k*256 + nn]);
    if (k == 0) {
        const float* B = (g==0)?bq:(g==1)?bk:(g==2)?bv:bsk;
        bias3[n] = B[nn];
    }
}

// generic fp32 -> bf16 elementwise convert (layout-preserving)
__global__ void cvt_f32_bf16(const float* __restrict__ in, __hip_bfloat16* __restrict__ out, int n)
{
    int i = blockIdx.x*256 + threadIdx.x;
    if (i < n) out[i] = f2bf(in[i]);
}

// ---------------- RGCN aggregation: one WAVE per (node,rel) key, unroll-4 ILP ----------------
__global__ __launch_bounds__(256) void agg1_kernel(const float* __restrict__ x,
                                                   const int* __restrict__ row_ptr,
                                                   const int* __restrict__ csr_src,
                                                   __hip_bfloat16* __restrict__ A1)
{
    int b = blockIdx.x*4 + (threadIdx.x >> 6);   // key = i*4 + r
    int lane = threadIdx.x & 63;
    int i = b >> 2, r = b & 3;
    int e0 = row_ptr[b], e1 = row_ptr[b+1];
    float sx0=0.f,sy0=0.f, sx1=0.f,sy1=0.f, sx2=0.f,sy2=0.f, sx3=0.f,sy3=0.f;
    int e = e0;
    for (; e+4 <= e1; e += 4) {
        int i0=csr_src[e], i1=csr_src[e+1], i2=csr_src[e+2], i3=csr_src[e+3];
        float2 v0 = *(const float2*)(x + (size_t)i0*IN_F + lane*2);
        float2 v1 = *(const float2*)(x + (size_t)i1*IN_F + lane*2);
        float2 v2 = *(const float2*)(x + (size_t)i2*IN_F + lane*2);
        float2 v3 = *(const float2*)(x + (size_t)i3*IN_F + lane*2);
        sx0+=v0.x; sy0+=v0.y; sx1+=v1.x; sy1+=v1.y;
        sx2+=v2.x; sy2+=v2.y; sx3+=v3.x; sy3+=v3.y;
    }
    for (; e < e1; e++) {
        int i0 = csr_src[e];
        float2 v = *(const float2*)(x + (size_t)i0*IN_F + lane*2);
        sx0+=v.x; sy0+=v.y;
    }
    float sx = (sx0+sx1)+(sx2+sx3);
    float sy = (sy0+sy1)+(sy2+sy3);
    float inv = (e1>e0) ? 1.f/(float)(e1-e0) : 0.f;
    *(unsigned*)(A1 + (size_t)i*640 + 128 + r*128 + lane*2) = pack_bf2(sx*inv, sy*inv);
    if (r == 0) {
        float2 v = *(const float2*)(x + (size_t)i*IN_F + lane*2);
        *(unsigned*)(A1 + (size_t)i*640 + lane*2) = pack_bf2(v.x, v.y);
    }
}

__global__ __launch_bounds__(256) void agg2_kernel(const int* __restrict__ row_ptr,
                                                   const int* __restrict__ csr_src,
                                                   __hip_bfloat16* __restrict__ A2)
{
    int b = blockIdx.x*4 + (threadIdx.x >> 6);
    int lane = threadIdx.x & 63;
    int i = b >> 2, r = b & 3;
    int e0 = row_ptr[b], e1 = row_ptr[b+1];
    float a0=0.f,a1=0.f,a2=0.f,a3=0.f;
    float b0=0.f,b1=0.f,b2=0.f,b3=0.f;
    float c0=0.f,c1=0.f,c2=0.f,c3=0.f;
    float d0=0.f,d1=0.f,d2=0.f,d3=0.f;
    int e = e0;
    for (; e+4 <= e1; e += 4) {
        int i0=csr_src[e], i1=csr_src[e+1], i2=csr_src[e+2], i3=csr_src[e+3];
        ushort4 u0 = *(const ushort4*)(A2 + (size_t)i0*1280 + lane*4);
        ushort4 u1 = *(const ushort4*)(A2 + (size_t)i1*1280 + lane*4);
        ushort4 u2 = *(const ushort4*)(A2 + (size_t)i2*1280 + lane*4);
        ushort4 u3 = *(const ushort4*)(A2 + (size_t)i3*1280 + lane*4);
        a0+=bfbits2f(u0.x); a1+=bfbits2f(u0.y); a2+=bfbits2f(u0.z); a3+=bfbits2f(u0.w);
        b0+=bfbits2f(u1.x); b1+=bfbits2f(u1.y); b2+=bfbits2f(u1.z); b3+=bfbits2f(u1.w);
        c0+=bfbits2f(u2.x); c1+=bfbits2f(u2.y); c2+=bfbits2f(u2.z); c3+=bfbits2f(u2.w);
        d0+=bfbits2f(u3.x); d1+=bfbits2f(u3.y); d2+=bfbits2f(u3.z); d3+=bfbits2f(u3.w);
    }
    for (; e < e1; e++) {
        int i0 = csr_src[e];
        ushort4 u = *(const ushort4*)(A2 + (size_t)i0*1280 + lane*4);
        a0+=bfbits2f(u.x); a1+=bfbits2f(u.y); a2+=bfbits2f(u.z); a3+=bfbits2f(u.w);
    }
    float s0=(a0+b0)+(c0+d0), s1=(a1+b1)+(c1+d1), s2=(a2+b2)+(c2+d2), s3=(a3+b3)+(c3+d3);
    float inv = (e1>e0) ? 1.f/(float)(e1-e0) : 0.f;
    uint2 w;
    w.x = pack_bf2(s0*inv, s1*inv);
    w.y = pack_bf2(s2*inv, s3*inv);
    *(uint2*)(A2 + (size_t)i*1280 + 256 + r*256 + lane*4) = w;
}

// ---------------- LDS-pipelined GEMM (r2 config: best measured) ----------------
// Triple-buffered global_load_lds, 2 batches in flight, counted vmcnt(L).
// Chunk-XOR LDS swizzle via pre-swizzled global source (0 bank conflicts, r1).
template<int MI>
__device__ __forceinline__ void gemm_bt_body(const __hip_bfloat16* __restrict__ A, int lda,
                                             const __hip_bfloat16* __restrict__ Bt,
                                             const float* __restrict__ bias,
                                             __hip_bfloat16* __restrict__ C, int ldc,
                                             int M, int K, int relu,
                                             int tile_m, int tile_n,
                                             __hip_bfloat16* lds_a, __hip_bfloat16* lds_b)
{
    constexpr int A_ELEMS = MI*1024;
    constexpr int B_ELEMS = 4096;
    constexpr int L = MI/2 + 2;
    const int tid  = threadIdx.x;
    const int wave = tid >> 6;
    const int lane = tid & 63;
    const int wm = wave >> 1, wn = wave & 1;
    const int fm = lane & 15;
    const int q  = lane >> 4;
    const int sw = (q ^ ((fm >> 1) & 3)) * 8;

    floatx4 acc[MI][4];
    #pragma unroll
    for (int i=0;i<MI;i++)
        #pragma unroll
        for (int j=0;j<4;j++) acc[i][j] = (floatx4){0.f,0.f,0.f,0.f};

    const int srow   = lane >> 2;
    const int schunk = lane & 3;
    size_t a_goff[MI/2];
    #pragma unroll
    for (int s = 0; s < MI/2; ++s) {
        int r = (s*4 + wave)*16 + srow;
        int c = schunk ^ ((r >> 1) & 3);
        a_goff[s] = (size_t)min(tile_m + r, M-1)*lda + c*8;
    }
    size_t b_goff[2];
    #pragma unroll
    for (int s = 0; s < 2; ++s) {
        int r = (s*4 + wave)*16 + srow;
        int c = schunk ^ ((r >> 1) & 3);
        b_goff[s] = (size_t)(tile_n + r)*K + c*8;
    }

    const int nt = K >> 5;

    auto issue = [&](int t, int bufi) {
        const int kn = t << 5;
        #pragma unroll
        for (int s = 0; s < MI/2; ++s)
            gload_lds16(A + a_goff[s] + kn, lds_a + bufi*A_ELEMS + (s*4 + wave)*512);
        #pragma unroll
        for (int s = 0; s < 2; ++s)
            gload_lds16(Bt + b_goff[s] + kn, lds_b + bufi*B_ELEMS + (s*4 + wave)*512);
    };

    issue(0, 0);
    if (nt > 1) { issue(1, 1); wait_vm<L>(); }
    else        { wait_vm<0>(); }
    __builtin_amdgcn_s_barrier();

    int cur = 0, nx2 = 2;
    for (int t = 0; t < nt; ++t) {
        if (t + 2 < nt) issue(t + 2, nx2);

        const __hip_bfloat16* la = lds_a + cur*A_ELEMS;
        const __hip_bfloat16* lb = lds_b + cur*B_ELEMS;
        short8 afr[MI], bfr[4];
        #pragma unroll
        for (int i=0;i<MI;i++)
            afr[i] = *(const short8*)(la + (wm*(MI*16) + i*16 + fm)*32 + sw);
        #pragma unroll
        for (int j=0;j<4;j++)
            bfr[j] = *(const short8*)(lb + (wn*64 + j*16 + fm)*32 + sw);

        __builtin_amdgcn_s_setprio(1);
        #pragma unroll
        for (int i=0;i<MI;i++)
            #pragma unroll
            for (int j=0;j<4;j++)
                acc[i][j] = __builtin_amdgcn_mfma_f32_16x16x32_bf16(afr[i], bfr[j], acc[i][j], 0,0,0);
        __builtin_amdgcn_s_setprio(0);

        if (t + 1 < nt) {
            if (t + 2 < nt) wait_vm<L>();
            else            wait_vm<0>();
            __builtin_amdgcn_s_barrier();
            cur = (cur == 2) ? 0 : cur + 1;
            nx2 = (nx2 == 2) ? 0 : nx2 + 1;
        }
    }

    const int crow_base = tile_m + wm*(MI*16);
    const int ccol_base = tile_n + wn*64;
    #pragma unroll
    for (int i=0;i<MI;i++) {
        #pragma unroll
        for (int j=0;j<4;j++) {
            int c  = ccol_base + j*16 + fm;
            float bb = bias[c];
            #pragma unroll
            for (int rg=0; rg<4; rg++) {
                int r = crow_base + i*16 + q*4 + rg;
                if (r < M) {
                    float v = acc[i][j][rg] + bb;
                    if (relu) v = fmaxf(v, 0.f);
                    C[(size_t)r*ldc + c] = f2bf(v);
                }
            }
        }
    }
}

template<int MI>
__global__ __launch_bounds__(256) void gemm_bt_t(const __hip_bfloat16* __restrict__ A, int lda,
                                                 const __hip_bfloat16* __restrict__ Bt,
                                                 const float* __restrict__ bias,
                                                 __hip_bfloat16* __restrict__ C, int ldc,
                                                 int M, int K, int relu)
{
    __shared__ __align__(16) __hip_bfloat16 lds_a[3*MI*1024];
    __shared__ __align__(16) __hip_bfloat16 lds_b[3*4096];
    int2 xy = xcd_swizzle();
    gemm_bt_body<MI>(A, lda, Bt, bias, C, ldc, M, K, relu,
                     xy.x*(MI*32), xy.y*128, lds_a, lds_b);
}

// ---------------- fused GRU gate-GEMM + elementwise (r6: 64x64 tile) ----------------
// r5 post-mortem: 64x32 tile had 4x-redundant B ds_reads (12 reads shared by all
// 4 waves) and tanhf cost ~15us of VALU. r6: block = 64 rows x 64 channels, 2x2
// wave grid (wave = 32 rows x 32 ch, 24 MFMA vs 16 ds_read per step, B redundancy
// 2x), double-buffered LDS 64 KB (2 blocks/CU, same as r5), r1-style flow with
// one batch in flight across each step (vmcnt(8), drain only at tail). Epilogue
// uses exp-based tanh/sigmoid (~6 ops vs libm tanhf ~25). Writes only fp32 out.
__global__ __launch_bounds__(256) void gemm_gru_fused(
    const __hip_bfloat16* __restrict__ A0,   // hatt bf16 [N,256]
    const __hip_bfloat16* __restrict__ A1,   // hprev bf16 [N,256]
    const __hip_bfloat16* __restrict__ Bt0,  // W_ih [768][256]
    const __hip_bfloat16* __restrict__ Bt1,  // W_hh [768][256]
    const float* __restrict__ b_ih, const float* __restrict__ b_hh,
    const float* __restrict__ hprev, float* __restrict__ out)
{
    constexpr int BUF_ELEMS = 16384;  // A 128x32 (4096) + B 384x32 (12288)
    __shared__ __align__(16) __hip_bfloat16 lds[2*BUF_ELEMS];   // 64 KB
    int2 xy = xcd_swizzle();          // grid (313, 4), y = 64-channel chunk
    const int tile_m = xy.x * 64;
    const int c0     = xy.y * 64;
    const int tid = threadIdx.x, wave = tid >> 6, lane = tid & 63;
    const int wm = wave >> 1, wn = wave & 1;     // 2x2 wave grid
    const int fm = lane & 15, q = lane >> 4;
    const int sw = (q ^ ((fm >> 1) & 3)) * 8;

    // 32 staging segments (16 frag-rows x 64 B each): 0..7 A, 8..31 B; 8/wave.
    // frag-row space: A = mat*64 + row_local (0..127); B = (mat*3+gate)*64 + ch_local (0..383)
    const int sub = lane >> 2, ch = lane & 3;
    const __hip_bfloat16* gsrc[8];
    int dstoff[8];
    #pragma unroll
    for (int s = 0; s < 8; ++s) {
        int seg = wave*8 + s;
        if (seg < 8) {
            int fr = seg*16 + sub;                   // 0..127
            int mat = fr >> 6, rl = fr & 63;
            int c = ch ^ ((fr >> 1) & 3);
            int grow = min(tile_m + rl, N_NODES-1);
            gsrc[s] = (mat ? A1 : A0) + (size_t)grow*256 + c*8;
            dstoff[s] = seg*512;
        } else {
            int fs = seg - 8;
            int fr = fs*16 + sub;                    // 0..383
            int grp = fr >> 6, ri = fr & 63;         // grp = mat*3 + gate
            int mat = grp >= 3, gate = mat ? grp-3 : grp;
            int c = ch ^ ((fr >> 1) & 3);
            int grow = gate*256 + c0 + ri;
            gsrc[s] = (mat ? Bt1 : Bt0) + (size_t)grow*256 + c*8;
            dstoff[s] = 4096 + fs*512;
        }
    }

    floatx4 acc[2][3][2][2];   // [mat][gate][row frag][col frag]
    #pragma unroll
    for (int m=0;m<2;m++)
        #pragma unroll
        for (int g=0;g<3;g++)
            #pragma unroll
            for (int i=0;i<2;i++)
                #pragma unroll
                for (int f=0;f<2;f++) acc[m][g][i][f] = (floatx4){0.f,0.f,0.f,0.f};

    auto issue = [&](int t, int bufi) {
        const int kn = t << 5;
        #pragma unroll
        for (int s = 0; s < 8; ++s)
            gload_lds16(gsrc[s] + kn, lds + bufi*BUF_ELEMS + dstoff[s]);
    };

    issue(0, 0);
    issue(1, 1);
    wait_vm<8>();                      // batch 0 landed; batch 1 in flight
    __builtin_amdgcn_s_barrier();

    #pragma unroll 1
    for (int t = 0; t < 8; ++t) {
        const __hip_bfloat16* lb = lds + (t & 1)*BUF_ELEMS;
        short8 af[2][2], bfr[2][3][2];
        #pragma unroll
        for (int m=0;m<2;m++)
            #pragma unroll
            for (int i=0;i<2;i++)
                af[m][i] = *(const short8*)(lb + (m*64 + wm*32 + i*16 + fm)*32 + sw);
        #pragma unroll
        for (int m=0;m<2;m++)
            #pragma unroll
            for (int g=0;g<3;g++)
                #pragma unroll
                for (int f=0;f<2;f++)
                    bfr[m][g][f] = *(const short8*)(lb + 4096 + (((m*3+g)*64 + wn*32 + f*16 + fm)*32) + sw);

        __builtin_amdgcn_s_setprio(1);
        #pragma unroll
        for (int m=0;m<2;m++)
            #pragma unroll
            for (int g=0;g<3;g++)
                #pragma unroll
                for (int i=0;i<2;i++)
                    #pragma unroll
                    for (int f=0;f<2;f++)
                        acc[m][g][i][f] = __builtin_amdgcn_mfma_f32_16x16x32_bf16(af[m][i], bfr[m][g][f], acc[m][g][i][f], 0,0,0);
        __builtin_amdgcn_s_setprio(0);

        if (t + 1 < 8) {
            __builtin_amdgcn_s_barrier();            // all waves done reading buf[t&1]
            if (t + 2 < 8) { issue(t + 2, t & 1); wait_vm<8>(); }  // t+1 landed, t+2 in flight
            else           wait_vm<0>();                           // tail drain
            __builtin_amdgcn_s_barrier();            // everyone's batch t+1 visible
        }
    }

    // epilogue: GRU math (exp-based sigmoid/tanh), write fp32 out only
    #pragma unroll
    for (int f=0; f<2; ++f) {
        int c = c0 + wn*32 + f*16 + fm;
        float bir = b_ih[c], biz = b_ih[256+c], bin = b_ih[512+c];
        float bhr = b_hh[c], bhz = b_hh[256+c], bhn = b_hh[512+c];
        #pragma unroll
        for (int i=0; i<2; ++i) {
            #pragma unroll
            for (int rg=0; rg<4; ++rg) {
                int r = tile_m + wm*32 + i*16 + q*4 + rg;
                if (r < N_NODES) {
                    float gir = acc[0][0][i][f][rg] + bir;
                    float giz = acc[0][1][i][f][rg] + biz;
                    float gin = acc[0][2][i][f][rg] + bin;
                    float ghr = acc[1][0][i][f][rg] + bhr;
                    float ghz = acc[1][1][i][f][rg] + bhz;
                    float ghn = acc[1][2][i][f][rg] + bhn;
                    float rr = 1.f/(1.f + __expf(-(gir + ghr)));
                    float zz = 1.f/(1.f + __expf(-(giz + ghz)));
                    float xn = gin + rr*ghn;
                    float e2 = __expf(xn + xn);
                    float nn = 1.f - 2.f/(e2 + 1.f);   // tanh(xn)
                    float h  = hprev[(size_t)r*256 + c];
                    out[(size_t)r*256 + c] = (1.f - zz)*nn + zz*h;
                }
            }
        }
    }
}

// ---------------- attention scores: ONE WAVE PER NODE ----------------
__global__ __launch_bounds__(256) void score_kernel(const __hip_bfloat16* __restrict__ qkvs,
                                                    const int* __restrict__ row_ptr,
                                                    const int* __restrict__ csr_src,
                                                    float* __restrict__ score)
{
    int i = blockIdx.x*4 + (threadIdx.x >> 6);
    int lane = threadIdx.x & 63;
    int h = lane >> 4, d4 = lane & 15;
    int e0 = row_ptr[i*R_REL], e1 = row_ptr[i*R_REL + R_REL];
    ushort4 qv = *(const ushort4*)(qkvs + (size_t)i*1024 + lane*4);
    float qx=bfbits2f(qv.x), qy=bfbits2f(qv.y), qz=bfbits2f(qv.z), qw=bfbits2f(qv.w);
    float* sp = score + (size_t)h*E_EDGES;
    int j = e0;
    for (; j+2 <= e1; j += 2) {
        int s0 = csr_src[j], s1 = csr_src[j+1];
        ushort4 k0 = *(const ushort4*)(qkvs + (size_t)s0*1024 + 256 + lane*4);
        ushort4 k1 = *(const ushort4*)(qkvs + (size_t)s1*1024 + 256 + lane*4);
        float d0 = qx*bfbits2f(k0.x)+qy*bfbits2f(k0.y)+qz*bfbits2f(k0.z)+qw*bfbits2f(k0.w);
        float d1 = qx*bfbits2f(k1.x)+qy*bfbits2f(k1.y)+qz*bfbits2f(k1.z)+qw*bfbits2f(k1.w);
        #pragma unroll
        for (int o=1;o<16;o<<=1){ d0 += __shfl_xor(d0,o,64); d1 += __shfl_xor(d1,o,64); }
        if (d4 == 0) { sp[j] = d0*0.125f; sp[j+1] = d1*0.125f; }
    }
    for (; j < e1; j++) {
        int s0 = csr_src[j];
        ushort4 k0 = *(const ushort4*)(qkvs + (size_t)s0*1024 + 256 + lane*4);
        float d0 = qx*bfbits2f(k0.x)+qy*bfbits2f(k0.y)+qz*bfbits2f(k0.z)+qw*bfbits2f(k0.w);
        #pragma unroll
        for (int o=1;o<16;o<<=1) d0 += __shfl_xor(d0,o,64);
        if (d4 == 0) sp[j] = d0*0.125f;
    }
}

// ---------------- attention aggregate: ONE WAVE PER NODE, all 4 heads ----------------
__global__ __launch_bounds__(256) void attn_agg_kernel(const __hip_bfloat16* __restrict__ qkvs,
                                                       const float* __restrict__ score,
                                                       const int* __restrict__ row_ptr,
                                                       const int* __restrict__ csr_src,
                                                       __hip_bfloat16* __restrict__ hatt)
{
    int i = blockIdx.x*4 + (threadIdx.x >> 6);   // node (4 nodes per block)
    int lane = threadIdx.x & 63;
    int h  = lane >> 4;
    int d4 = lane & 15;
    int e0 = row_ptr[i*R_REL], e1 = row_ptr[i*R_REL + R_REL];
    int deg = e1 - e0;
    const float* sp = score + (size_t)h*E_EDGES + e0;

    float m = -1e30f;
    for (int j = d4; j < deg; j += 16) m = fmaxf(m, sp[j]);
    #pragma unroll
    for (int o=1;o<16;o<<=1) m = fmaxf(m, __shfl_xor(m, o, 64));

    float ssum = 0.f;
    for (int j = d4; j < deg; j += 16) ssum += __expf(sp[j] - m);
    #pragma unroll
    for (int o=1;o<16;o<<=1) ssum += __shfl_xor(ssum, o, 64);
    float inv = 1.f / fmaxf(ssum, 1e-16f);

    float ax=0.f, ay=0.f, az=0.f, aw=0.f;
    int j = 0;
    for (; j+4 <= deg; j += 4) {
        int s0=csr_src[e0+j], s1=csr_src[e0+j+1], s2=csr_src[e0+j+2], s3=csr_src[e0+j+3];
        float w0 = __expf(sp[j]   - m) * inv;
        float w1 = __expf(sp[j+1] - m) * inv;
        float w2 = __expf(sp[j+2] - m) * inv;
        float w3 = __expf(sp[j+3] - m) * inv;
        ushort4 u0 = *(const ushort4*)(qkvs + (size_t)s0*1024 + 512 + lane*4);
        ushort4 u1 = *(const ushort4*)(qkvs + (size_t)s1*1024 + 512 + lane*4);
        ushort4 u2 = *(const ushort4*)(qkvs + (size_t)s2*1024 + 512 + lane*4);
        ushort4 u3 = *(const ushort4*)(qkvs + (size_t)s3*1024 + 512 + lane*4);
        ax += w0*bfbits2f(u0.x) + w1*bfbits2f(u1.x) + w2*bfbits2f(u2.x) + w3*bfbits2f(u3.x);
        ay += w0*bfbits2f(u0.y) + w1*bfbits2f(u1.y) + w2*bfbits2f(u2.y) + w3*bfbits2f(u3.y);
        az += w0*bfbits2f(u0.z) + w1*bfbits2f(u1.z) + w2*bfbits2f(u2.z) + w3*bfbits2f(u3.z);
        aw += w0*bfbits2f(u0.w) + w1*bfbits2f(u1.w) + w2*bfbits2f(u2.w) + w3*bfbits2f(u3.w);
    }
    for (; j < deg; j++) {
        int s = csr_src[e0+j];
        float w = __expf(sp[j] - m) * inv;
        ushort4 u = *(const ushort4*)(qkvs + (size_t)s*1024 + 512 + lane*4);
        ax += w*bfbits2f(u.x); ay += w*bfbits2f(u.y);
        az += w*bfbits2f(u.z); aw += w*bfbits2f(u.w);
    }
    ushort4 sk = *(const ushort4*)(qkvs + (size_t)i*1024 + 768 + lane*4);
    uint2 w;
    w.x = pack_bf2(ax + bfbits2f(sk.x), ay + bfbits2f(sk.y));
    w.y = pack_bf2(az + bfbits2f(sk.z), aw + bfbits2f(sk.w));
    *(uint2*)(hatt + (size_t)i*256 + lane*4) = w;
}

// ---------------- launch ----------------
extern "C" void kernel_launch(void* const* d_in, const int* in_sizes, int n_in,
                              void* d_out, int out_size, void* d_ws, size_t ws_size,
                              hipStream_t stream)
{
    const float* x       = (const float*)d_in[0];
    const int* edge_index= (const int*)d_in[1];
    const int* edge_type = (const int*)d_in[2];
    const float* hprev   = (const float*)d_in[3];
    const float* W1      = (const float*)d_in[4];
    const float* root1   = (const float*)d_in[5];
    const float* b1      = (const float*)d_in[6];
    const float* W2      = (const float*)d_in[7];
    const float* root2   = (const float*)d_in[8];
    const float* b2      = (const float*)d_in[9];
    const float* Wq      = (const float*)d_in[10];
    const float* bq      = (const float*)d_in[11];
    const float* Wk      = (const float*)d_in[12];
    const float* bk      = (const float*)d_in[13];
    const float* Wv      = (const float*)d_in[14];
    const float* bv      = (const float*)d_in[15];
    const float* Wskip   = (const float*)d_in[16];
    const float* bskip   = (const float*)d_in[17];
    const float* W_ih    = (const float*)d_in[18];
    const float* b_ih    = (const float*)d_in[19];
    const float* W_hh    = (const float*)d_in[20];
    const float* b_hh    = (const float*)d_in[21];

    char* ws = (char*)d_ws;
    size_t off = 0;
    auto take = [&](size_t bytes)->char* {
        char* p = ws + off;
        off = (off + bytes + 255) & ~(size_t)255;
        return p;
    };
    int* cnt        = (int*)take((size_t)NRKEYS*4);
    int* row_ptr    = (int*)take((size_t)(NRKEYS+1)*4);
    int* cursor     = (int*)take((size_t)NRKEYS*4);
    int* csr_src    = (int*)take((size_t)E_EDGES*4);
    int* blocksum   = (int*)take((size_t)SCAN_BLOCKS*4);
    int* blockoff   = (int*)take((size_t)(SCAN_BLOCKS+1)*4);
    float* score    = (float*)take((size_t)R_REL*E_EDGES*4);
    __hip_bfloat16* B1t   = (__hip_bfloat16*)take((size_t)256*640*2);
    __hip_bfloat16* B2t   = (__hip_bfloat16*)take((size_t)256*1280*2);
    __hip_bfloat16* B3t   = (__hip_bfloat16*)take((size_t)1024*256*2);
    __hip_bfloat16* Biht  = (__hip_bfloat16*)take((size_t)768*256*2);
    __hip_bfloat16* Bhht  = (__hip_bfloat16*)take((size_t)768*256*2);
    float*          bias3 = (float*)take((size_t)1024*4);
    __hip_bfloat16* hprev_bf = (__hip_bfloat16*)take((size_t)N_NODES*256*2);
    char* P1 = take((size_t)N_NODES*640*2);
    char* P2 = take((size_t)N_NODES*1536*2);

    __hip_bfloat16* A1   = (__hip_bfloat16*)P1;   // [N,640]  dead after gemm1
    __hip_bfloat16* h2   = (__hip_bfloat16*)P1;   // [N,256]  dead after gemm3
    __hip_bfloat16* hatt = (__hip_bfloat16*)P1;   // [N,256]  read by fused GRU
    __hip_bfloat16* A2   = (__hip_bfloat16*)P2;   // [N,1280] dead after gemm2
    __hip_bfloat16* qkvs = (__hip_bfloat16*)P2;   // [N,1024] dead after attn_agg

    hipMemsetAsync(cnt, 0, (size_t)NRKEYS*4, stream);
    count_kernel<<<(E_EDGES+255)/256, 256, 0, stream>>>(edge_index, edge_type, cnt);
    scan_reduce_kernel<<<SCAN_BLOCKS, 1024, 0, stream>>>(cnt, blocksum);
    scan_sums_kernel<<<1, 128, 0, stream>>>(blocksum, blockoff);
    scan_apply_kernel<<<SCAN_BLOCKS, 1024, 0, stream>>>(cnt, blockoff, row_ptr, cursor);
    fill_kernel<<<(E_EDGES+255)/256, 256, 0, stream>>>(edge_index, edge_type, cursor, csr_src);

    make_b1t<<<(256*640+255)/256, 256, 0, stream>>>(root1, W1, B1t);
    make_b2t<<<(256*1280+255)/256, 256, 0, stream>>>(root2, W2, B2t);
    make_b3t<<<(1024*256+255)/256, 256, 0, stream>>>(Wq, Wk, Wv, Wskip, bq, bk, bv, bskip, B3t, bias3);
    cvt_f32_bf16<<<(768*256+255)/256, 256, 0, stream>>>(W_ih, Biht, 768*256);
    cvt_f32_bf16<<<(768*256+255)/256, 256, 0, stream>>>(W_hh, Bhht, 768*256);
    cvt_f32_bf16<<<(N_NODES*256+255)/256, 256, 0, stream>>>(hprev, hprev_bf, N_NODES*256);

    agg1_kernel<<<NRKEYS/4, 256, 0, stream>>>(x, row_ptr, csr_src, A1);

    // h1 = relu(A1 * B1) written into A2 cols 0..255 (ldc=1280)
    dim3 g12(313, 2);
    gemm_bt_t<2><<<g12, 256, 0, stream>>>(A1, 640, B1t, b1, A2, 1280, N_NODES, 640, 1);

    agg2_kernel<<<NRKEYS/4, 256, 0, stream>>>(row_ptr, csr_src, A2);

    // h2 overwrites A1 (dead) in P1
    gemm_bt_t<2><<<g12, 256, 0, stream>>>(A2, 1280, B2t, b2, h2, 256, N_NODES, 1280, 1);

    // qkvs overwrites A2 (dead) in P2
    dim3 g3(157, 8);
    gemm_bt_t<4><<<g3, 256, 0, stream>>>(h2, 256, B3t, bias3, qkvs, 1024, N_NODES, 256, 0);

    score_kernel<<<N_NODES/4, 256, 0, stream>>>(qkvs, row_ptr, csr_src, score);
    attn_agg_kernel<<<N_NODES/4, 256, 0, stream>>>(qkvs, score, row_ptr, csr_src, hatt);

    // fused GRU gate-GEMMs + elementwise: writes fp32 out directly (64x64 tiles)
    gemm_gru_fused<<<dim3(313, 4), 256, 0, stream>>>(hatt, hprev_bf, Biht, Bhht,
                                                     b_ih, b_hh, hprev, (float*)d_out);
}